// Round 4
// baseline (813.700 us; speedup 1.0000x reference)
//
#include <hip/hip_runtime.h>
#include <hip/hip_bf16.h>
#include <cstdint>
#include <cfloat>
#include <climits>

// Problem constants (setup_inputs: B=2, T=4096, D=1024, F=4096, S=4096)
#define BB   2
#define TT   4096
#define DD   1024
#define FF   4096
#define SS   4096
#define MTOK (BB * TT)   // 8192 tokens
#define NCHUNK 32
#define TCHUNK 128

typedef __bf16 bf16x8 __attribute__((ext_vector_type(8)));
typedef float  f32x4  __attribute__((ext_vector_type(4)));
typedef __attribute__((address_space(3))) char lds_char;
typedef __attribute__((address_space(1))) char g_char;

// top-2 merge with (value desc, index asc) total order — exact jax top_k tie
// semantics. Merges (w0,j0,w1,j1) into (v0,i0,v1,i1).
#define TKMERGE(w0, j0, w1, j1)                                              \
  {                                                                          \
    if (w0 > v0 || (w0 == v0 && j0 < i0)) {                                  \
      float t0v = v0; int t0i = i0; v0 = w0; i0 = j0;                        \
      if (t0v > w1 || (t0v == w1 && t0i < j1)) { v1 = t0v; i1 = t0i; }       \
      else { v1 = w1; i1 = j1; }                                             \
    } else {                                                                 \
      if (w0 > v1 || (w0 == v1 && j0 < i1)) { v1 = w0; i1 = j0; }            \
    }                                                                        \
  }

// ---------------------------------------------------------------------------
// batched fp32 -> bf16 convert for all 9 weight matrices in one dispatch.
// mode 0: linear copy. mode 1/2: gate/up row interleave for the fused FFN.
// ---------------------------------------------------------------------------
struct CvtArgs {
  const float* src[9];
  __hip_bfloat16* dst[9];
  int off4[10];  // prefix sums of float4 counts
  int mode[9];
};

__global__ __launch_bounds__(256) void cvt_all_kernel(CvtArgs a) {
  int g = blockIdx.x * 256 + threadIdx.x;
  if (g >= a.off4[9]) return;
  int s = 0;
  while (g >= a.off4[s + 1]) s++;
  int i = g - a.off4[s];
  float4 v = ((const float4*)a.src[s])[i];
  union { ushort4 u; __hip_bfloat16 h[4]; } p;
  p.h[0] = __float2bfloat16(v.x);
  p.h[1] = __float2bfloat16(v.y);
  p.h[2] = __float2bfloat16(v.z);
  p.h[3] = __float2bfloat16(v.w);
  int di = i;
  int m = a.mode[s];
  if (m) {
    int r = i >> 8, c = i & 255;
    int dr = ((r >> 4) << 5) + (r & 15) + ((m == 2) ? 16 : 0);
    di = (dr << 8) + c;
  }
  ((ushort4*)a.dst[s])[di] = p.u;
}

// ---------------------------------------------------------------------------
// combine the 3 causal depthwise kernels into one 15-tap (padded to 16) table
// ---------------------------------------------------------------------------
__global__ void wcomb_kernel(const float* __restrict__ w3, const float* __restrict__ w7,
                             const float* __restrict__ w15, float* __restrict__ wc) {
  int d = blockIdx.x * 256 + threadIdx.x;
  if (d >= DD) return;
  for (int j = 0; j < 16; j++) {
    float v = 0.f;
    if (j < 15) {
      v = w15[d * 15 + (14 - j)];
      if (j < 7) v += w7[d * 7 + (6 - j)];
      if (j < 3) v += w3[d * 3 + (2 - j)];
    }
    wc[d * 16 + j] = v;
  }
}

// ---------------------------------------------------------------------------
// RMSNorm: one block per row of 1024, fp32 in, bf16 out
// ---------------------------------------------------------------------------
__global__ __launch_bounds__(256) void rms_kernel(const float* __restrict__ x,
                                                  const float* __restrict__ w,
                                                  __hip_bfloat16* __restrict__ ob) {
  const int row = blockIdx.x;
  const int tid = threadIdx.x;
  float4 v = ((const float4*)(x + (size_t)row * DD))[tid];
  float ss = v.x * v.x + v.y * v.y + v.z * v.z + v.w * v.w;
  for (int off = 32; off > 0; off >>= 1) ss += __shfl_down(ss, off, 64);
  __shared__ float wsum[4];
  if ((tid & 63) == 0) wsum[tid >> 6] = ss;
  __syncthreads();
  float tot = wsum[0] + wsum[1] + wsum[2] + wsum[3];
  float rinv = 1.0f / sqrtf(tot * (1.0f / DD) + 1e-6f);
  float4 wg = ((const float4*)w)[tid];
  union { ushort4 u; __hip_bfloat16 h[4]; } p;
  p.h[0] = __float2bfloat16(v.x * wg.x * rinv);
  p.h[1] = __float2bfloat16(v.y * wg.y * rinv);
  p.h[2] = __float2bfloat16(v.z * wg.z * rinv);
  p.h[3] = __float2bfloat16(v.w * wg.w * rinv);
  ((ushort4*)ob)[(size_t)row * 256 + tid] = p.u;
}

// ---------------------------------------------------------------------------
// multi-scale causal depthwise conv, 15 taps combined, LDS tiled with halo
// ---------------------------------------------------------------------------
__global__ __launch_bounds__(256) void conv_kernel(const __hip_bfloat16* __restrict__ xn,
                                                   const float* __restrict__ wc,
                                                   __hip_bfloat16* __restrict__ outp) {
  __shared__ float xt[78][64];
  __shared__ float wt[64][15];
  const int b = blockIdx.z, t0 = blockIdx.x * 64, d0 = blockIdx.y * 64;
  const int tid = threadIdx.x;
  const int dl = tid & 63;
  for (int idx = tid; idx < 64 * 15; idx += 256) {
    int d = idx / 15, j = idx % 15;
    wt[d][j] = wc[(d0 + d) * 16 + j];
  }
  for (int r = tid >> 6; r < 78; r += 4) {
    int t = t0 - 14 + r;
    xt[r][dl] = (t >= 0) ? __bfloat162float(xn[((size_t)b * TT + t) * DD + d0 + dl]) : 0.f;
  }
  __syncthreads();
  for (int tl = tid >> 6; tl < 64; tl += 4) {
    float acc = 0.f;
#pragma unroll
    for (int j = 0; j < 15; j++) acc += wt[dl][j] * xt[tl + 14 - j][dl];
    outp[((size_t)b * TT + t0 + tl) * DD + d0 + dl] = __float2bfloat16(acc);
  }
}

// ---------------------------------------------------------------------------
// bf16 GEMM, C[M,N] = A[M,K] @ B[N,K]^T, m97 structure, 128x128 tile, BK=32.
// SWZ 0: m-sliced XCD swizzle (XCD owns contiguous M-tiles x all N) — good
//        when the per-XCD operand slices fit L2 (small N or small K).
// SWZ 1: weight-stationary N-sliced swizzle: XCD owns nT/8 N-tiles x all M,
//        n-fastest order. B-slice stays hot in the 4MB XCD-L2; A-tile reused
//        across the slice via adjacency. Requires nT % 8 == 0.
// Epilogues:
//  1: z/htilde: bias + sigmoid on cols<1024, bf16 out (N=2048)
//  2: outb = bf16(acc)
//  6: split-K fp32 partial: outf[z*M*N + idx] = acc
//  7: fused FFN: j-even tile = gate, j-odd = up; outb = bf16(silu(g)*u)
//  8: scores top-2: per-row top-2 candidates over the 128-col tile ->
//     outf as float4 cand[row][nblk] = {v0, v1, bits(i0), bits(i1)}
// ---------------------------------------------------------------------------
template <int EPI, int KSPLIT = 1, int SWZ = 0>
__global__ __launch_bounds__(256, 2) void gemm_bt(
    const __hip_bfloat16* __restrict__ A, const __hip_bfloat16* __restrict__ Bm,
    const int M, const int N, const int K,
    float* __restrict__ outf, __hip_bfloat16* __restrict__ outb,
    const float* __restrict__ bias0, const float* __restrict__ bias1) {
  __shared__ __align__(16) __hip_bfloat16 As[128 * 32];
  __shared__ __align__(16) __hip_bfloat16 Bs[128 * 32];
  const int tid = threadIdx.x;
  const int lane = tid & 63;
  const int wave = tid >> 6;
  const int fm = lane & 15, fq = lane >> 4;

  const int nT = gridDim.x;
  const int lin = blockIdx.y * nT + blockIdx.x;
  int tileM, tileN;
  if constexpr (SWZ == 0) {
    const int xcd = lin & 7;
    const int idx_ = lin >> 3;
    const int mq = idx_ / nT;
    tileM = (xcd * (gridDim.y >> 3) + mq) * 128;
    tileN = (idx_ - mq * nT) * 128;
  } else {
    const int xcd = lin & 7;
    const int idx_ = lin >> 3;
    const int nS = nT >> 3;
    const int m = idx_ / nS;
    const int nl = idx_ - m * nS;
    tileM = m * 128;
    tileN = (xcd * nS + nl) * 128;
  }

  const int wm = (wave & 1) * 64, wn = (wave >> 1) * 64;

  f32x4 acc[4][4] = {};

  const int srow = tid >> 2;
  const int scol = (tid & 3) * 8;
  const __hip_bfloat16* gA = A + (size_t)(tileM + srow) * K + scol;
  const __hip_bfloat16* gB = Bm + (size_t)(tileN + srow) * K + scol;
  lds_char* ldsA = (lds_char*)(&As[0]);
  lds_char* ldsB = (lds_char*)(&Bs[0]);
  const int wbyte = wave * 1024;

  const int kPer = K / KSPLIT;
  const int kBeg = (KSPLIT > 1) ? blockIdx.z * kPer : 0;
  for (int k0 = kBeg; k0 < kBeg + kPer; k0 += 32) {
    __syncthreads();
    __builtin_amdgcn_global_load_lds((g_char*)(void*)(gA + k0),                  ldsA + wbyte,        16, 0, 0);
    __builtin_amdgcn_global_load_lds((g_char*)(void*)(gA + k0 + (size_t)64 * K), ldsA + wbyte + 4096, 16, 0, 0);
    __builtin_amdgcn_global_load_lds((g_char*)(void*)(gB + k0),                  ldsB + wbyte,        16, 0, 0);
    __builtin_amdgcn_global_load_lds((g_char*)(void*)(gB + k0 + (size_t)64 * K), ldsB + wbyte + 4096, 16, 0, 0);
    __syncthreads();
    bf16x8 af[4], bfr[4];
#pragma unroll
    for (int i = 0; i < 4; i++) {
      af[i]  = *(const bf16x8*)(As + (wm + i * 16 + fm) * 32 + fq * 8);
      bfr[i] = *(const bf16x8*)(Bs + (wn + i * 16 + fm) * 32 + fq * 8);
    }
#pragma unroll
    for (int i = 0; i < 4; i++)
#pragma unroll
      for (int j = 0; j < 4; j++)
        acc[i][j] = __builtin_amdgcn_mfma_f32_16x16x32_bf16(af[i], bfr[j], acc[i][j], 0, 0, 0);
  }

  // epilogue: C/D layout col = lane&15, row = (lane>>4)*4 + reg  [m89/m91]
  if constexpr (EPI == 7) {
#pragma unroll
    for (int i = 0; i < 4; i++) {
#pragma unroll
      for (int j = 0; j < 4; j += 2) {
        const int ffcol = (((tileN + wn + j * 16) >> 5) << 4) + fm;
#pragma unroll
        for (int r = 0; r < 4; r++) {
          const int rw = tileM + wm + i * 16 + fq * 4 + r;
          float g = acc[i][j][r];
          float u = acc[i][j + 1][r];
          float v = g / (1.f + __expf(-g)) * u;
          outb[(size_t)rw * FF + ffcol] = __float2bfloat16(v);
        }
      }
    }
  } else if constexpr (EPI == 8) {
    __syncthreads();  // MFMA LDS reads done; safe to reuse LDS space below
    __shared__ float lv[128][2];
    __shared__ int   li[128][2];
#pragma unroll
    for (int i = 0; i < 4; i++) {
#pragma unroll
      for (int r = 0; r < 4; r++) {
        float v0 = -FLT_MAX, v1 = -FLT_MAX;
        int i0 = INT_MAX, i1 = INT_MAX;
#pragma unroll
        for (int j = 0; j < 4; j++) {
          float v = acc[i][j][r];
          int c = tileN + wn + j * 16 + fm;
          if (v > v0) { v1 = v0; i1 = i0; v0 = v; i0 = c; }
          else if (v > v1) { v1 = v; i1 = c; }
        }
        // butterfly over the 16 fm lanes (same fq group)
#pragma unroll
        for (int off = 1; off < 16; off <<= 1) {
          float w0 = __shfl_xor(v0, off, 64), w1 = __shfl_xor(v1, off, 64);
          int   j0 = __shfl_xor(i0, off, 64), j1 = __shfl_xor(i1, off, 64);
          TKMERGE(w0, j0, w1, j1);
        }
        const int lrow = wm + i * 16 + fq * 4 + r;
        if (wn == 64 && fm == 0) {
          lv[lrow][0] = v0; lv[lrow][1] = v1;
          li[lrow][0] = i0; li[lrow][1] = i1;
        }
      }
    }
    __syncthreads();
    if (wn == 0) {
#pragma unroll
      for (int i = 0; i < 4; i++) {
#pragma unroll
        for (int r = 0; r < 4; r++) {
          // redo the local reduction result? No — recompute is wasteful; we
          // instead kept values: note each (i,r) pass above left v0.. in regs
          // only for the last (i,r). So redo per-(i,r) from acc:
          float v0 = -FLT_MAX, v1 = -FLT_MAX;
          int i0 = INT_MAX, i1 = INT_MAX;
#pragma unroll
          for (int j = 0; j < 4; j++) {
            float v = acc[i][j][r];
            int c = tileN + wn + j * 16 + fm;
            if (v > v0) { v1 = v0; i1 = i0; v0 = v; i0 = c; }
            else if (v > v1) { v1 = v; i1 = c; }
          }
#pragma unroll
          for (int off = 1; off < 16; off <<= 1) {
            float w0 = __shfl_xor(v0, off, 64), w1 = __shfl_xor(v1, off, 64);
            int   j0 = __shfl_xor(i0, off, 64), j1 = __shfl_xor(i1, off, 64);
            TKMERGE(w0, j0, w1, j1);
          }
          const int lrow = wm + i * 16 + fq * 4 + r;
          if (fm == 0) {
            float w0 = lv[lrow][0], w1 = lv[lrow][1];
            int   j0 = li[lrow][0], j1 = li[lrow][1];
            TKMERGE(w0, j0, w1, j1);
            float4 c4;
            c4.x = v0; c4.y = v1;
            c4.z = __int_as_float(i0); c4.w = __int_as_float(i1);
            ((float4*)outf)[(size_t)(tileM + lrow) * (SS / 128) + (tileN >> 7)] = c4;
          }
        }
      }
    }
  } else {
#pragma unroll
    for (int i = 0; i < 4; i++) {
#pragma unroll
      for (int j = 0; j < 4; j++) {
        const int c = tileN + wn + j * 16 + fm;
#pragma unroll
        for (int r = 0; r < 4; r++) {
          const int rw = tileM + wm + i * 16 + fq * 4 + r;
          const size_t idx = (size_t)rw * N + c;
          float v = acc[i][j][r];
          if constexpr (EPI == 1) {
            v += (c < DD) ? bias0[c] : bias1[c - DD];
            if (c < DD) v = 1.f / (1.f + __expf(-v));
            outb[idx] = __float2bfloat16(v);
          } else if constexpr (EPI == 2) {
            outb[idx] = __float2bfloat16(v);
          } else if constexpr (EPI == 6) {
            outf[(size_t)blockIdx.z * M * N + idx] = v;
          }
        }
      }
    }
  }
}

// ---------------------------------------------------------------------------
// 64x128 (MxN) tile variant for grid-limited N=1024 GEMMs (mix/q/projout).
// ---------------------------------------------------------------------------
template <int EPI>
__global__ __launch_bounds__(256, 4) void gemm_bt64(
    const __hip_bfloat16* __restrict__ A, const __hip_bfloat16* __restrict__ Bm,
    const int M, const int N, const int K,
    const float* __restrict__ resid, float* __restrict__ outf,
    __hip_bfloat16* __restrict__ outb) {
  __shared__ __align__(16) __hip_bfloat16 As[64 * 32];
  __shared__ __align__(16) __hip_bfloat16 Bs[128 * 32];
  const int tid = threadIdx.x;
  const int lane = tid & 63;
  const int wave = tid >> 6;
  const int fm = lane & 15, fq = lane >> 4;

  const int nT = gridDim.x;
  const int lin = blockIdx.y * nT + blockIdx.x;
  const int xcd = lin & 7;
  const int idx_ = lin >> 3;
  const int mq = idx_ / nT;
  const int tileM = (xcd * (gridDim.y >> 3) + mq) * 64;
  const int tileN = (idx_ - mq * nT) * 128;

  const int wm = (wave & 1) * 32, wn = (wave >> 1) * 64;

  f32x4 acc[2][4] = {};

  const int srow = tid >> 2;
  const int scol = (tid & 3) * 8;
  const __hip_bfloat16* gA = A + (size_t)(tileM + srow) * K + scol;
  const __hip_bfloat16* gB = Bm + (size_t)(tileN + srow) * K + scol;
  lds_char* ldsA = (lds_char*)(&As[0]);
  lds_char* ldsB = (lds_char*)(&Bs[0]);
  const int wbyte = wave * 1024;

  for (int k0 = 0; k0 < K; k0 += 32) {
    __syncthreads();
    __builtin_amdgcn_global_load_lds((g_char*)(void*)(gA + k0),                  ldsA + wbyte,        16, 0, 0);
    __builtin_amdgcn_global_load_lds((g_char*)(void*)(gB + k0),                  ldsB + wbyte,        16, 0, 0);
    __builtin_amdgcn_global_load_lds((g_char*)(void*)(gB + k0 + (size_t)64 * K), ldsB + wbyte + 4096, 16, 0, 0);
    __syncthreads();
    bf16x8 af[2], bfr[4];
#pragma unroll
    for (int i = 0; i < 2; i++)
      af[i]  = *(const bf16x8*)(As + (wm + i * 16 + fm) * 32 + fq * 8);
#pragma unroll
    for (int j = 0; j < 4; j++)
      bfr[j] = *(const bf16x8*)(Bs + (wn + j * 16 + fm) * 32 + fq * 8);
#pragma unroll
    for (int i = 0; i < 2; i++)
#pragma unroll
      for (int j = 0; j < 4; j++)
        acc[i][j] = __builtin_amdgcn_mfma_f32_16x16x32_bf16(af[i], bfr[j], acc[i][j], 0, 0, 0);
  }

#pragma unroll
  for (int i = 0; i < 2; i++) {
#pragma unroll
    for (int j = 0; j < 4; j++) {
      const int c = tileN + wn + j * 16 + fm;
#pragma unroll
      for (int r = 0; r < 4; r++) {
        const int rw = tileM + wm + i * 16 + fq * 4 + r;
        const size_t idx = (size_t)rw * N + c;
        float v = acc[i][j][r];
        if constexpr (EPI == 0) {
          outf[idx] = resid[idx] + v;
        } else {
          outb[idx] = __float2bfloat16(v);
        }
      }
    }
  }
}

// ---------------------------------------------------------------------------
// split-K fixup for the down projection: out = resid + P0 + P1
// ---------------------------------------------------------------------------
__global__ __launch_bounds__(256) void reduce_down(const float* __restrict__ P,
                                                   const float* __restrict__ resid,
                                                   float* __restrict__ out) {
  size_t i = (size_t)blockIdx.x * 256 + threadIdx.x;
  float4 a = ((const float4*)P)[i];
  float4 b = ((const float4*)(P + (size_t)MTOK * DD))[i];
  float4 rr = ((const float4*)resid)[i];
  float4 o;
  o.x = rr.x + a.x + b.x; o.y = rr.y + a.y + b.y;
  o.z = rr.z + a.z + b.z; o.w = rr.w + a.w + b.w;
  ((float4*)out)[i] = o;
}

// ---------------------------------------------------------------------------
// MinGRU chunked parallel scan over zht [MTOK, 2048] bf16 (z | htilde)
// ---------------------------------------------------------------------------
__global__ __launch_bounds__(256) void scan_pass1(const __hip_bfloat16* __restrict__ zht,
                                                  float* __restrict__ cA,
                                                  float* __restrict__ cB) {
  const int b = blockIdx.z, c = blockIdx.y;
  const int d = blockIdx.x * 256 + threadIdx.x;
  const __hip_bfloat16* base = zht + (size_t)b * TT * 2048;
  float A = 1.f, Bc = 0.f;
  const int t0 = c * TCHUNK;
  for (int t = t0; t < t0 + TCHUNK; t++) {
    const __hip_bfloat16* rowp = base + (size_t)t * 2048;
    float z = __bfloat162float(rowp[d]);
    float h = __bfloat162float(rowp[DD + d]);
    float om = 1.f - z;
    A *= om;
    Bc = om * Bc + z * h;
  }
  size_t idx = ((size_t)b * NCHUNK + c) * DD + d;
  cA[idx] = A;
  cB[idx] = Bc;
}

__global__ __launch_bounds__(256) void scan_pass2(const float* __restrict__ hp,
                                                  const float* __restrict__ cA,
                                                  const float* __restrict__ cB,
                                                  float* __restrict__ hstart,
                                                  float* __restrict__ hlast) {
  const int b = blockIdx.y;
  const int d = blockIdx.x * 256 + threadIdx.x;
  float h = hp[b * DD + d];
  for (int c = 0; c < NCHUNK; c++) {
    size_t idx = ((size_t)b * NCHUNK + c) * DD + d;
    hstart[idx] = h;
    h = cA[idx] * h + cB[idx];
  }
  hlast[b * DD + d] = h;
}

__global__ __launch_bounds__(256) void scan_pass3(const __hip_bfloat16* __restrict__ zht,
                                                  const float* __restrict__ hstart,
                                                  float* __restrict__ x) {
  const int b = blockIdx.z, c = blockIdx.y;
  const int d = blockIdx.x * 256 + threadIdx.x;
  const __hip_bfloat16* base = zht + (size_t)b * TT * 2048;
  float h = hstart[((size_t)b * NCHUNK + c) * DD + d];
  const int t0 = c * TCHUNK;
  for (int t = t0; t < t0 + TCHUNK; t++) {
    const __hip_bfloat16* rowp = base + (size_t)t * 2048;
    float z = __bfloat162float(rowp[d]);
    float ht = __bfloat162float(rowp[DD + d]);
    h = (1.f - z) * h + z * ht;
    x[((size_t)b * TT + t) * DD + d] += h;
  }
}

// ---------------------------------------------------------------------------
// merge 32 per-tile top-2 candidates per row -> global top-2, softmax, gather.
// One wave per row; 4 rows per block.
// ---------------------------------------------------------------------------
__global__ __launch_bounds__(256) void topk_merge(const float4* __restrict__ cand,
                                                  const float* __restrict__ sv,
                                                  __hip_bfloat16* __restrict__ ret) {
  const int row = blockIdx.x * 4 + (threadIdx.x >> 6);
  const int lane = threadIdx.x & 63;
  float v0 = -FLT_MAX, v1 = -FLT_MAX;
  int i0 = INT_MAX, i1 = INT_MAX;
  if (lane < 32) {
    float4 c = cand[(size_t)row * 32 + lane];
    v0 = c.x; v1 = c.y;
    i0 = __float_as_int(c.z); i1 = __float_as_int(c.w);
  }
#pragma unroll
  for (int off = 1; off < 64; off <<= 1) {
    float w0 = __shfl_xor(v0, off, 64), w1 = __shfl_xor(v1, off, 64);
    int   j0 = __shfl_xor(i0, off, 64), j1 = __shfl_xor(i1, off, 64);
    TKMERGE(w0, j0, w1, j1);
  }
  float s0 = v0 * (1.f / 32.f), s1 = v1 * (1.f / 32.f);  // /sqrt(D)
  float e = __expf(s1 - s0);
  float denom = 1.f + e;
  float a0 = 1.f / denom;
  float a1 = e / denom;
  const float4* r0 = (const float4*)(sv + (size_t)i0 * DD);
  const float4* r1 = (const float4*)(sv + (size_t)i1 * DD);
#pragma unroll
  for (int k = 0; k < 4; k++) {
    int j = lane + 64 * k;
    float4 u = r0[j], w4 = r1[j];
    union { ushort4 u; __hip_bfloat16 h[4]; } p;
    p.h[0] = __float2bfloat16(a0 * u.x + a1 * w4.x);
    p.h[1] = __float2bfloat16(a0 * u.y + a1 * w4.y);
    p.h[2] = __float2bfloat16(a0 * u.z + a1 * w4.z);
    p.h[3] = __float2bfloat16(a0 * u.w + a1 * w4.w);
    ((ushort4*)(ret + (size_t)row * DD))[j] = p.u;
  }
}

// ---------------------------------------------------------------------------
extern "C" void kernel_launch(void* const* d_in, const int* in_sizes, int n_in,
                              void* d_out, int out_size, void* d_ws, size_t ws_size,
                              hipStream_t stream) {
  (void)in_sizes; (void)n_in; (void)out_size; (void)ws_size;
  const float* x_in   = (const float*)d_in[0];
  const float* h_prev = (const float*)d_in[1];
  const float* n1w    = (const float*)d_in[2];
  const float* w3     = (const float*)d_in[3];
  const float* w7     = (const float*)d_in[4];
  const float* w15    = (const float*)d_in[5];
  const float* mixw   = (const float*)d_in[6];
  const float* n2w    = (const float*)d_in[7];
  const float* wzw    = (const float*)d_in[8];
  const float* wzb    = (const float*)d_in[9];
  const float* whw    = (const float*)d_in[10];
  const float* whb    = (const float*)d_in[11];
  const float* n3w    = (const float*)d_in[12];
  const float* slotk  = (const float*)d_in[13];
  const float* slotv  = (const float*)d_in[14];
  const float* pqw    = (const float*)d_in[15];
  const float* pow_   = (const float*)d_in[16];
  const float* n4w    = (const float*)d_in[17];
  const float* gatew  = (const float*)d_in[18];
  const float* upw    = (const float*)d_in[19];
  const float* downw  = (const float*)d_in[20];
  float* out = (float*)d_out;

  char* ws = (char*)d_ws;
  size_t o = 0;
  auto alloc = [&](size_t bytes) {
    size_t r = o;
    o += (bytes + 255) & ~(size_t)255;
    return r;
  };
  __hip_bfloat16* wmix = (__hip_bfloat16*)(ws + alloc((size_t)DD * DD * 2));
  __hip_bfloat16* wzht = (__hip_bfloat16*)(ws + alloc((size_t)2 * DD * DD * 2));
  __hip_bfloat16* wpq  = (__hip_bfloat16*)(ws + alloc((size_t)DD * DD * 2));
  __hip_bfloat16* wsk  = (__hip_bfloat16*)(ws + alloc((size_t)SS * DD * 2));
  __hip_bfloat16* wpo  = (__hip_bfloat16*)(ws + alloc((size_t)DD * DD * 2));
  __hip_bfloat16* wfu  = (__hip_bfloat16*)(ws + alloc((size_t)2 * FF * DD * 2));  // gate/up interleaved
  __hip_bfloat16* wd   = (__hip_bfloat16*)(ws + alloc((size_t)DD * FF * 2));
  float* wcomb = (float*)(ws + alloc((size_t)DD * 16 * 4));
  float* xws   = (float*)(ws + alloc((size_t)MTOK * DD * 4));
  __hip_bfloat16* xnb  = (__hip_bfloat16*)(ws + alloc((size_t)MTOK * DD * 2));
  __hip_bfloat16* qb   = (__hip_bfloat16*)(ws + alloc((size_t)MTOK * DD * 2));
  __hip_bfloat16* retr = (__hip_bfloat16*)(ws + alloc((size_t)MTOK * DD * 2));
  float* scanA  = (float*)(ws + alloc((size_t)BB * NCHUNK * DD * 4));
  float* scanB  = (float*)(ws + alloc((size_t)BB * NCHUNK * DD * 4));
  float* hstart = (float*)(ws + alloc((size_t)BB * NCHUNK * DD * 4));
  char* big = ws + alloc((size_t)MTOK * FF * 4);  // 134 MB shared region
  // aliases (lifetimes disjoint):
  __hip_bfloat16* xn1b  = (__hip_bfloat16*)big;                            // phase 1
  __hip_bfloat16* convb = (__hip_bfloat16*)(big + (size_t)MTOK * DD * 2);  // phase 1
  __hip_bfloat16* zhtb  = (__hip_bfloat16*)big;                            // phase 2
  float* candf          = (float*)big;                                     // phase 3 (4 MB)
  __hip_bfloat16* ffin  = (__hip_bfloat16*)big;                            // phase 4
  float* Pbuf           = (float*)(big + (size_t)MTOK * FF * 2);           // phase 4 (2x33.5MB)

  // weight conversions — one batched dispatch (gate/up row-interleaved)
  {
    CvtArgs a;
    const float* srcs[9] = {mixw, wzw, whw, pqw, slotk, pow_, gatew, upw, downw};
    __hip_bfloat16* dsts[9] = {wmix, wzht, wzht + (size_t)DD * DD, wpq, wsk, wpo, wfu, wfu, wd};
    int n4s[9] = {DD * DD / 4, DD * DD / 4, DD * DD / 4, DD * DD / 4, SS * DD / 4,
                  DD * DD / 4, FF * DD / 4, FF * DD / 4, DD * FF / 4};
    int modes[9] = {0, 0, 0, 0, 0, 0, 1, 2, 0};
    int acc_ = 0;
    for (int i = 0; i < 9; i++) {
      a.src[i] = srcs[i]; a.dst[i] = dsts[i]; a.off4[i] = acc_; a.mode[i] = modes[i];
      acc_ += n4s[i];
    }
    a.off4[9] = acc_;
    cvt_all_kernel<<<(acc_ + 255) / 256, 256, 0, stream>>>(a);
  }
  wcomb_kernel<<<DD / 256, 256, 0, stream>>>(w3, w7, w15, wcomb);

  // 1. conv block
  rms_kernel<<<MTOK, 256, 0, stream>>>(x_in, n1w, xn1b);
  conv_kernel<<<dim3(TT / 64, DD / 64, BB), 256, 0, stream>>>(xn1b, wcomb, convb);
  gemm_bt64<0><<<dim3(DD / 128, MTOK / 64), 256, 0, stream>>>(
      convb, wmix, MTOK, DD, DD, x_in, xws, nullptr);

  // 2. MinGRU
  rms_kernel<<<MTOK, 256, 0, stream>>>(xws, n2w, xnb);
  gemm_bt<1, 1, 1><<<dim3(2048 / 128, MTOK / 128), 256, 0, stream>>>(
      xnb, wzht, MTOK, 2048, DD, nullptr, zhtb, wzb, whb);
  scan_pass1<<<dim3(DD / 256, NCHUNK, BB), 256, 0, stream>>>(zhtb, scanA, scanB);
  scan_pass2<<<dim3(DD / 256, BB), 256, 0, stream>>>(h_prev, scanA, scanB, hstart,
                                                     out + (size_t)MTOK * DD);
  scan_pass3<<<dim3(DD / 256, NCHUNK, BB), 256, 0, stream>>>(zhtb, hstart, xws);

  // 3. slot memory (top-2 fused into scores GEMM epilogue)
  rms_kernel<<<MTOK, 256, 0, stream>>>(xws, n3w, xnb);
  gemm_bt64<2><<<dim3(DD / 128, MTOK / 64), 256, 0, stream>>>(
      xnb, wpq, MTOK, DD, DD, nullptr, nullptr, qb);
  gemm_bt<8, 1, 1><<<dim3(SS / 128, MTOK / 128), 256, 0, stream>>>(
      qb, wsk, MTOK, SS, DD, candf, nullptr, nullptr, nullptr);
  topk_merge<<<MTOK / 4, 256, 0, stream>>>((const float4*)candf, slotv, retr);
  gemm_bt64<0><<<dim3(DD / 128, MTOK / 64), 256, 0, stream>>>(
      retr, wpo, MTOK, DD, DD, xws, xws, nullptr);

  // 4. SwiGLU FFN (fused gate+up, then split-K down + reduce)
  rms_kernel<<<MTOK, 256, 0, stream>>>(xws, n4w, xnb);
  gemm_bt<7, 1, 1><<<dim3(2 * FF / 128, MTOK / 128), 256, 0, stream>>>(
      xnb, wfu, MTOK, 2 * FF, DD, nullptr, ffin, nullptr, nullptr);
  gemm_bt<6, 2, 0><<<dim3(DD / 128, MTOK / 128, 2), 256, 0, stream>>>(
      ffin, wd, MTOK, DD, FF, Pbuf, nullptr, nullptr, nullptr);
  reduce_down<<<MTOK * DD / 1024, 256, 0, stream>>>(Pbuf, xws, out);
}

// Round 5
// 795.355 us; speedup vs baseline: 1.0231x; 1.0231x over previous
//
#include <hip/hip_runtime.h>
#include <hip/hip_bf16.h>
#include <cstdint>
#include <cfloat>
#include <climits>

// Problem constants (setup_inputs: B=2, T=4096, D=1024, F=4096, S=4096)
#define BB   2
#define TT   4096
#define DD   1024
#define FF   4096
#define SS   4096
#define MTOK (BB * TT)   // 8192 tokens
#define NCHUNK 32
#define TCHUNK 128

typedef __bf16 bf16x8 __attribute__((ext_vector_type(8)));
typedef float  f32x4  __attribute__((ext_vector_type(4)));
typedef __attribute__((address_space(3))) char lds_char;
typedef __attribute__((address_space(1))) char g_char;

// top-2 merge with (value desc, index asc) total order — exact jax top_k tie
// semantics. Merges (w0,j0,w1,j1) into (v0,i0,v1,i1).
#define TKMERGE(w0, j0, w1, j1)                                              \
  {                                                                          \
    if (w0 > v0 || (w0 == v0 && j0 < i0)) {                                  \
      float t0v = v0; int t0i = i0; v0 = w0; i0 = j0;                        \
      if (t0v > w1 || (t0v == w1 && t0i < j1)) { v1 = t0v; i1 = t0i; }       \
      else { v1 = w1; i1 = j1; }                                             \
    } else {                                                                 \
      if (w0 > v1 || (w0 == v1 && j0 < i1)) { v1 = w0; i1 = j0; }            \
    }                                                                        \
  }

// ---------------------------------------------------------------------------
// batched fp32 -> bf16 convert for all 9 weight matrices in one dispatch.
// mode 0: linear copy. mode 1/2: gate/up row interleave for the fused FFN.
// mode 3: 1024x1024 transpose (for projq^T, consumed as GEMM B operand).
// ---------------------------------------------------------------------------
struct CvtArgs {
  const float* src[9];
  __hip_bfloat16* dst[9];
  int off4[10];  // prefix sums of float4 counts
  int mode[9];
};

__global__ __launch_bounds__(256) void cvt_all_kernel(CvtArgs a) {
  int g = blockIdx.x * 256 + threadIdx.x;
  if (g >= a.off4[9]) return;
  int s = 0;
  while (g >= a.off4[s + 1]) s++;
  int i = g - a.off4[s];
  float4 v = ((const float4*)a.src[s])[i];
  union { ushort4 u; __hip_bfloat16 h[4]; } p;
  p.h[0] = __float2bfloat16(v.x);
  p.h[1] = __float2bfloat16(v.y);
  p.h[2] = __float2bfloat16(v.z);
  p.h[3] = __float2bfloat16(v.w);
  int m = a.mode[s];
  if (m == 3) {
    // src row r (K' index), cols c4*4+k -> dst[col*1024 + r]
    int r = i >> 8, c4 = i & 255;
#pragma unroll
    for (int k = 0; k < 4; k++)
      a.dst[s][(size_t)(c4 * 4 + k) * 1024 + r] = p.h[k];
    return;
  }
  int di = i;
  if (m == 1 || m == 2) {
    int r = i >> 8, c = i & 255;
    int dr = ((r >> 4) << 5) + (r & 15) + ((m == 2) ? 16 : 0);
    di = (dr << 8) + c;
  }
  ((ushort4*)a.dst[s])[di] = p.u;
}

// ---------------------------------------------------------------------------
// combine the 3 causal depthwise kernels into one 15-tap (padded to 16) table
// ---------------------------------------------------------------------------
__global__ void wcomb_kernel(const float* __restrict__ w3, const float* __restrict__ w7,
                             const float* __restrict__ w15, float* __restrict__ wc) {
  int d = blockIdx.x * 256 + threadIdx.x;
  if (d >= DD) return;
  for (int j = 0; j < 16; j++) {
    float v = 0.f;
    if (j < 15) {
      v = w15[d * 15 + (14 - j)];
      if (j < 7) v += w7[d * 7 + (6 - j)];
      if (j < 3) v += w3[d * 3 + (2 - j)];
    }
    wc[d * 16 + j] = v;
  }
}

// ---------------------------------------------------------------------------
// RMSNorm: one block per row of 1024, fp32 in, bf16 out
// ---------------------------------------------------------------------------
__global__ __launch_bounds__(256) void rms_kernel(const float* __restrict__ x,
                                                  const float* __restrict__ w,
                                                  __hip_bfloat16* __restrict__ ob) {
  const int row = blockIdx.x;
  const int tid = threadIdx.x;
  float4 v = ((const float4*)(x + (size_t)row * DD))[tid];
  float ss = v.x * v.x + v.y * v.y + v.z * v.z + v.w * v.w;
  for (int off = 32; off > 0; off >>= 1) ss += __shfl_down(ss, off, 64);
  __shared__ float wsum[4];
  if ((tid & 63) == 0) wsum[tid >> 6] = ss;
  __syncthreads();
  float tot = wsum[0] + wsum[1] + wsum[2] + wsum[3];
  float rinv = 1.0f / sqrtf(tot * (1.0f / DD) + 1e-6f);
  float4 wg = ((const float4*)w)[tid];
  union { ushort4 u; __hip_bfloat16 h[4]; } p;
  p.h[0] = __float2bfloat16(v.x * wg.x * rinv);
  p.h[1] = __float2bfloat16(v.y * wg.y * rinv);
  p.h[2] = __float2bfloat16(v.z * wg.z * rinv);
  p.h[3] = __float2bfloat16(v.w * wg.w * rinv);
  ((ushort4*)ob)[(size_t)row * 256 + tid] = p.u;
}

// ---------------------------------------------------------------------------
// multi-scale causal depthwise conv, 15 taps combined, LDS tiled with halo
// ---------------------------------------------------------------------------
__global__ __launch_bounds__(256) void conv_kernel(const __hip_bfloat16* __restrict__ xn,
                                                   const float* __restrict__ wc,
                                                   __hip_bfloat16* __restrict__ outp) {
  __shared__ float xt[78][64];
  __shared__ float wt[64][15];
  const int b = blockIdx.z, t0 = blockIdx.x * 64, d0 = blockIdx.y * 64;
  const int tid = threadIdx.x;
  const int dl = tid & 63;
  for (int idx = tid; idx < 64 * 15; idx += 256) {
    int d = idx / 15, j = idx % 15;
    wt[d][j] = wc[(d0 + d) * 16 + j];
  }
  for (int r = tid >> 6; r < 78; r += 4) {
    int t = t0 - 14 + r;
    xt[r][dl] = (t >= 0) ? __bfloat162float(xn[((size_t)b * TT + t) * DD + d0 + dl]) : 0.f;
  }
  __syncthreads();
  for (int tl = tid >> 6; tl < 64; tl += 4) {
    float acc = 0.f;
#pragma unroll
    for (int j = 0; j < 15; j++) acc += wt[dl][j] * xt[tl + 14 - j][dl];
    outp[((size_t)b * TT + t0 + tl) * DD + d0 + dl] = __float2bfloat16(acc);
  }
}

// ---------------------------------------------------------------------------
// bf16 GEMM, C[M,N] = A[M,K] @ B[N,K]^T, m97 structure, 128x128 tile, BK=32.
// SWZ 0: m-sliced XCD swizzle — use when B per XCD fits L2 (N*K*2/8-ish small).
// SWZ 1: weight-stationary N-sliced swizzle — use for large-N weight GEMMs
//        (B-slice nS*128*K*2 stays hot per XCD; A streams through L3).
// Epilogues:
//  1: z/htilde: bias + sigmoid on cols<1024, bf16 out (N=2048)
//  2: outb = bf16(acc)
//  6: split-K fp32 partial: outf[z*M*N + idx] = acc
//  7: fused FFN: j-even tile = gate, j-odd = up; outb = bf16(silu(g)*u)
//  8: scores top-2: per-row top-2 candidates over the 128-col tile ->
//     outf as float4 cand[row][nblk] = {v0, v1, bits(i0), bits(i1)}
// ---------------------------------------------------------------------------
template <int EPI, int KSPLIT = 1, int SWZ = 0>
__global__ __launch_bounds__(256, 2) void gemm_bt(
    const __hip_bfloat16* __restrict__ A, const __hip_bfloat16* __restrict__ Bm,
    const int M, const int N, const int K,
    float* __restrict__ outf, __hip_bfloat16* __restrict__ outb,
    const float* __restrict__ bias0, const float* __restrict__ bias1) {
  __shared__ __align__(16) __hip_bfloat16 As[128 * 32];
  __shared__ __align__(16) __hip_bfloat16 Bs[128 * 32];
  const int tid = threadIdx.x;
  const int lane = tid & 63;
  const int wave = tid >> 6;
  const int fm = lane & 15, fq = lane >> 4;

  const int nT = gridDim.x;
  const int lin = blockIdx.y * nT + blockIdx.x;
  int tileM, tileN;
  if constexpr (SWZ == 0) {
    const int xcd = lin & 7;
    const int idx_ = lin >> 3;
    const int mq = idx_ / nT;
    tileM = (xcd * (gridDim.y >> 3) + mq) * 128;
    tileN = (idx_ - mq * nT) * 128;
  } else {
    const int xcd = lin & 7;
    const int idx_ = lin >> 3;
    const int nS = nT >> 3;
    const int m = idx_ / nS;
    const int nl = idx_ - m * nS;
    tileM = m * 128;
    tileN = (xcd * nS + nl) * 128;
  }

  const int wm = (wave & 1) * 64, wn = (wave >> 1) * 64;

  f32x4 acc[4][4] = {};

  const int srow = tid >> 2;
  const int scol = (tid & 3) * 8;
  const __hip_bfloat16* gA = A + (size_t)(tileM + srow) * K + scol;
  const __hip_bfloat16* gB = Bm + (size_t)(tileN + srow) * K + scol;
  lds_char* ldsA = (lds_char*)(&As[0]);
  lds_char* ldsB = (lds_char*)(&Bs[0]);
  const int wbyte = wave * 1024;

  const int kPer = K / KSPLIT;
  const int kBeg = (KSPLIT > 1) ? blockIdx.z * kPer : 0;
  for (int k0 = kBeg; k0 < kBeg + kPer; k0 += 32) {
    __syncthreads();
    __builtin_amdgcn_global_load_lds((g_char*)(void*)(gA + k0),                  ldsA + wbyte,        16, 0, 0);
    __builtin_amdgcn_global_load_lds((g_char*)(void*)(gA + k0 + (size_t)64 * K), ldsA + wbyte + 4096, 16, 0, 0);
    __builtin_amdgcn_global_load_lds((g_char*)(void*)(gB + k0),                  ldsB + wbyte,        16, 0, 0);
    __builtin_amdgcn_global_load_lds((g_char*)(void*)(gB + k0 + (size_t)64 * K), ldsB + wbyte + 4096, 16, 0, 0);
    __syncthreads();
    bf16x8 af[4], bfr[4];
#pragma unroll
    for (int i = 0; i < 4; i++) {
      af[i]  = *(const bf16x8*)(As + (wm + i * 16 + fm) * 32 + fq * 8);
      bfr[i] = *(const bf16x8*)(Bs + (wn + i * 16 + fm) * 32 + fq * 8);
    }
#pragma unroll
    for (int i = 0; i < 4; i++)
#pragma unroll
      for (int j = 0; j < 4; j++)
        acc[i][j] = __builtin_amdgcn_mfma_f32_16x16x32_bf16(af[i], bfr[j], acc[i][j], 0, 0, 0);
  }

  // epilogue: C/D layout col = lane&15, row = (lane>>4)*4 + reg  [m89/m91]
  if constexpr (EPI == 7) {
#pragma unroll
    for (int i = 0; i < 4; i++) {
#pragma unroll
      for (int j = 0; j < 4; j += 2) {
        const int ffcol = (((tileN + wn + j * 16) >> 5) << 4) + fm;
#pragma unroll
        for (int r = 0; r < 4; r++) {
          const int rw = tileM + wm + i * 16 + fq * 4 + r;
          float g = acc[i][j][r];
          float u = acc[i][j + 1][r];
          float v = g / (1.f + __expf(-g)) * u;
          outb[(size_t)rw * FF + ffcol] = __float2bfloat16(v);
        }
      }
    }
  } else if constexpr (EPI == 8) {
    // single pass: both wave halves (wn=0 / wn=64) deposit their per-row
    // top-2 into LDS; one barrier; 128 threads merge + write candidate.
    __shared__ float lv2[2][128][2];
    __shared__ int   li2[2][128][2];
    const int half = wn >> 6;
#pragma unroll
    for (int i = 0; i < 4; i++) {
#pragma unroll
      for (int r = 0; r < 4; r++) {
        float v0 = -FLT_MAX, v1 = -FLT_MAX;
        int i0 = INT_MAX, i1 = INT_MAX;
#pragma unroll
        for (int j = 0; j < 4; j++) {
          float v = acc[i][j][r];
          int c = tileN + wn + j * 16 + fm;
          if (v > v0) { v1 = v0; i1 = i0; v0 = v; i0 = c; }
          else if (v > v1) { v1 = v; i1 = c; }
        }
#pragma unroll
        for (int off = 1; off < 16; off <<= 1) {
          float w0 = __shfl_xor(v0, off, 64), w1 = __shfl_xor(v1, off, 64);
          int   j0 = __shfl_xor(i0, off, 64), j1 = __shfl_xor(i1, off, 64);
          TKMERGE(w0, j0, w1, j1);
        }
        if (fm == 0) {
          const int lrow = wm + i * 16 + fq * 4 + r;
          lv2[half][lrow][0] = v0; lv2[half][lrow][1] = v1;
          li2[half][lrow][0] = i0; li2[half][lrow][1] = i1;
        }
      }
    }
    __syncthreads();
    if (tid < 128) {
      float v0 = lv2[0][tid][0], v1 = lv2[0][tid][1];
      int   i0 = li2[0][tid][0], i1 = li2[0][tid][1];
      float w0 = lv2[1][tid][0], w1 = lv2[1][tid][1];
      int   j0 = li2[1][tid][0], j1 = li2[1][tid][1];
      TKMERGE(w0, j0, w1, j1);
      float4 c4;
      c4.x = v0; c4.y = v1;
      c4.z = __int_as_float(i0); c4.w = __int_as_float(i1);
      ((float4*)outf)[(size_t)(tileM + tid) * (SS / 128) + (tileN >> 7)] = c4;
    }
  } else {
#pragma unroll
    for (int i = 0; i < 4; i++) {
#pragma unroll
      for (int j = 0; j < 4; j++) {
        const int c = tileN + wn + j * 16 + fm;
#pragma unroll
        for (int r = 0; r < 4; r++) {
          const int rw = tileM + wm + i * 16 + fq * 4 + r;
          const size_t idx = (size_t)rw * N + c;
          float v = acc[i][j][r];
          if constexpr (EPI == 1) {
            v += (c < DD) ? bias0[c] : bias1[c - DD];
            if (c < DD) v = 1.f / (1.f + __expf(-v));
            outb[idx] = __float2bfloat16(v);
          } else if constexpr (EPI == 2) {
            outb[idx] = __float2bfloat16(v);
          } else if constexpr (EPI == 6) {
            outf[(size_t)blockIdx.z * M * N + idx] = v;
          }
        }
      }
    }
  }
}

// ---------------------------------------------------------------------------
// 64x128 (MxN) tile variant for grid-limited N=1024 GEMMs (mix/projout).
// ---------------------------------------------------------------------------
template <int EPI>
__global__ __launch_bounds__(256, 4) void gemm_bt64(
    const __hip_bfloat16* __restrict__ A, const __hip_bfloat16* __restrict__ Bm,
    const int M, const int N, const int K,
    const float* __restrict__ resid, float* __restrict__ outf,
    __hip_bfloat16* __restrict__ outb) {
  __shared__ __align__(16) __hip_bfloat16 As[64 * 32];
  __shared__ __align__(16) __hip_bfloat16 Bs[128 * 32];
  const int tid = threadIdx.x;
  const int lane = tid & 63;
  const int wave = tid >> 6;
  const int fm = lane & 15, fq = lane >> 4;

  const int nT = gridDim.x;
  const int lin = blockIdx.y * nT + blockIdx.x;
  const int xcd = lin & 7;
  const int idx_ = lin >> 3;
  const int mq = idx_ / nT;
  const int tileM = (xcd * (gridDim.y >> 3) + mq) * 64;
  const int tileN = (idx_ - mq * nT) * 128;

  const int wm = (wave & 1) * 32, wn = (wave >> 1) * 64;

  f32x4 acc[2][4] = {};

  const int srow = tid >> 2;
  const int scol = (tid & 3) * 8;
  const __hip_bfloat16* gA = A + (size_t)(tileM + srow) * K + scol;
  const __hip_bfloat16* gB = Bm + (size_t)(tileN + srow) * K + scol;
  lds_char* ldsA = (lds_char*)(&As[0]);
  lds_char* ldsB = (lds_char*)(&Bs[0]);
  const int wbyte = wave * 1024;

  for (int k0 = 0; k0 < K; k0 += 32) {
    __syncthreads();
    __builtin_amdgcn_global_load_lds((g_char*)(void*)(gA + k0),                  ldsA + wbyte,        16, 0, 0);
    __builtin_amdgcn_global_load_lds((g_char*)(void*)(gB + k0),                  ldsB + wbyte,        16, 0, 0);
    __builtin_amdgcn_global_load_lds((g_char*)(void*)(gB + k0 + (size_t)64 * K), ldsB + wbyte + 4096, 16, 0, 0);
    __syncthreads();
    bf16x8 af[2], bfr[4];
#pragma unroll
    for (int i = 0; i < 2; i++)
      af[i]  = *(const bf16x8*)(As + (wm + i * 16 + fm) * 32 + fq * 8);
#pragma unroll
    for (int j = 0; j < 4; j++)
      bfr[j] = *(const bf16x8*)(Bs + (wn + j * 16 + fm) * 32 + fq * 8);
#pragma unroll
    for (int i = 0; i < 2; i++)
#pragma unroll
      for (int j = 0; j < 4; j++)
        acc[i][j] = __builtin_amdgcn_mfma_f32_16x16x32_bf16(af[i], bfr[j], acc[i][j], 0, 0, 0);
  }

#pragma unroll
  for (int i = 0; i < 2; i++) {
#pragma unroll
    for (int j = 0; j < 4; j++) {
      const int c = tileN + wn + j * 16 + fm;
#pragma unroll
      for (int r = 0; r < 4; r++) {
        const int rw = tileM + wm + i * 16 + fq * 4 + r;
        const size_t idx = (size_t)rw * N + c;
        float v = acc[i][j][r];
        if constexpr (EPI == 0) {
          outf[idx] = resid[idx] + v;
        } else {
          outb[idx] = __float2bfloat16(v);
        }
      }
    }
  }
}

// ---------------------------------------------------------------------------
// split-K fixup for the down projection: out = resid + P0 + P1
// ---------------------------------------------------------------------------
__global__ __launch_bounds__(256) void reduce_down(const float* __restrict__ P,
                                                   const float* __restrict__ resid,
                                                   float* __restrict__ out) {
  size_t i = (size_t)blockIdx.x * 256 + threadIdx.x;
  float4 a = ((const float4*)P)[i];
  float4 b = ((const float4*)(P + (size_t)MTOK * DD))[i];
  float4 rr = ((const float4*)resid)[i];
  float4 o;
  o.x = rr.x + a.x + b.x; o.y = rr.y + a.y + b.y;
  o.z = rr.z + a.z + b.z; o.w = rr.w + a.w + b.w;
  ((float4*)out)[i] = o;
}

// ---------------------------------------------------------------------------
// MinGRU chunked parallel scan over zht [MTOK, 2048] bf16 (z | htilde)
// ---------------------------------------------------------------------------
__global__ __launch_bounds__(256) void scan_pass1(const __hip_bfloat16* __restrict__ zht,
                                                  float* __restrict__ cA,
                                                  float* __restrict__ cB) {
  const int b = blockIdx.z, c = blockIdx.y;
  const int d = blockIdx.x * 256 + threadIdx.x;
  const __hip_bfloat16* base = zht + (size_t)b * TT * 2048;
  float A = 1.f, Bc = 0.f;
  const int t0 = c * TCHUNK;
  for (int t = t0; t < t0 + TCHUNK; t++) {
    const __hip_bfloat16* rowp = base + (size_t)t * 2048;
    float z = __bfloat162float(rowp[d]);
    float h = __bfloat162float(rowp[DD + d]);
    float om = 1.f - z;
    A *= om;
    Bc = om * Bc + z * h;
  }
  size_t idx = ((size_t)b * NCHUNK + c) * DD + d;
  cA[idx] = A;
  cB[idx] = Bc;
}

__global__ __launch_bounds__(256) void scan_pass2(const float* __restrict__ hp,
                                                  const float* __restrict__ cA,
                                                  const float* __restrict__ cB,
                                                  float* __restrict__ hstart,
                                                  float* __restrict__ hlast) {
  const int b = blockIdx.y;
  const int d = blockIdx.x * 256 + threadIdx.x;
  float h = hp[b * DD + d];
  for (int c = 0; c < NCHUNK; c++) {
    size_t idx = ((size_t)b * NCHUNK + c) * DD + d;
    hstart[idx] = h;
    h = cA[idx] * h + cB[idx];
  }
  hlast[b * DD + d] = h;
}

__global__ __launch_bounds__(256) void scan_pass3(const __hip_bfloat16* __restrict__ zht,
                                                  const float* __restrict__ hstart,
                                                  float* __restrict__ x) {
  const int b = blockIdx.z, c = blockIdx.y;
  const int d = blockIdx.x * 256 + threadIdx.x;
  const __hip_bfloat16* base = zht + (size_t)b * TT * 2048;
  float h = hstart[((size_t)b * NCHUNK + c) * DD + d];
  const int t0 = c * TCHUNK;
  for (int t = t0; t < t0 + TCHUNK; t++) {
    const __hip_bfloat16* rowp = base + (size_t)t * 2048;
    float z = __bfloat162float(rowp[d]);
    float ht = __bfloat162float(rowp[DD + d]);
    h = (1.f - z) * h + z * ht;
    x[((size_t)b * TT + t) * DD + d] += h;
  }
}

// ---------------------------------------------------------------------------
// merge 32 per-tile top-2 candidates per row -> global top-2, softmax, gather.
// One wave per row; 4 rows per block.
// ---------------------------------------------------------------------------
__global__ __launch_bounds__(256) void topk_merge(const float4* __restrict__ cand,
                                                  const float* __restrict__ sv,
                                                  __hip_bfloat16* __restrict__ ret) {
  const int row = blockIdx.x * 4 + (threadIdx.x >> 6);
  const int lane = threadIdx.x & 63;
  float v0 = -FLT_MAX, v1 = -FLT_MAX;
  int i0 = INT_MAX, i1 = INT_MAX;
  if (lane < 32) {
    float4 c = cand[(size_t)row * 32 + lane];
    v0 = c.x; v1 = c.y;
    i0 = __float_as_int(c.z); i1 = __float_as_int(c.w);
  }
#pragma unroll
  for (int off = 1; off < 64; off <<= 1) {
    float w0 = __shfl_xor(v0, off, 64), w1 = __shfl_xor(v1, off, 64);
    int   j0 = __shfl_xor(i0, off, 64), j1 = __shfl_xor(i1, off, 64);
    TKMERGE(w0, j0, w1, j1);
  }
  float s0 = v0 * (1.f / 32.f), s1 = v1 * (1.f / 32.f);  // /sqrt(D)
  float e = __expf(s1 - s0);
  float denom = 1.f + e;
  float a0 = 1.f / denom;
  float a1 = e / denom;
  const float4* r0 = (const float4*)(sv + (size_t)i0 * DD);
  const float4* r1 = (const float4*)(sv + (size_t)i1 * DD);
#pragma unroll
  for (int k = 0; k < 4; k++) {
    int j = lane + 64 * k;
    float4 u = r0[j], w4 = r1[j];
    union { ushort4 u; __hip_bfloat16 h[4]; } p;
    p.h[0] = __float2bfloat16(a0 * u.x + a1 * w4.x);
    p.h[1] = __float2bfloat16(a0 * u.y + a1 * w4.y);
    p.h[2] = __float2bfloat16(a0 * u.z + a1 * w4.z);
    p.h[3] = __float2bfloat16(a0 * u.w + a1 * w4.w);
    ((ushort4*)(ret + (size_t)row * DD))[j] = p.u;
  }
}

// ---------------------------------------------------------------------------
extern "C" void kernel_launch(void* const* d_in, const int* in_sizes, int n_in,
                              void* d_out, int out_size, void* d_ws, size_t ws_size,
                              hipStream_t stream) {
  (void)in_sizes; (void)n_in; (void)out_size; (void)ws_size;
  const float* x_in   = (const float*)d_in[0];
  const float* h_prev = (const float*)d_in[1];
  const float* n1w    = (const float*)d_in[2];
  const float* w3     = (const float*)d_in[3];
  const float* w7     = (const float*)d_in[4];
  const float* w15    = (const float*)d_in[5];
  const float* mixw   = (const float*)d_in[6];
  const float* n2w    = (const float*)d_in[7];
  const float* wzw    = (const float*)d_in[8];
  const float* wzb    = (const float*)d_in[9];
  const float* whw    = (const float*)d_in[10];
  const float* whb    = (const float*)d_in[11];
  const float* n3w    = (const float*)d_in[12];
  const float* slotk  = (const float*)d_in[13];
  const float* slotv  = (const float*)d_in[14];
  const float* pqw    = (const float*)d_in[15];
  const float* pow_   = (const float*)d_in[16];
  const float* n4w    = (const float*)d_in[17];
  const float* gatew  = (const float*)d_in[18];
  const float* upw    = (const float*)d_in[19];
  const float* downw  = (const float*)d_in[20];
  float* out = (float*)d_out;

  char* ws = (char*)d_ws;
  size_t o = 0;
  auto alloc = [&](size_t bytes) {
    size_t r = o;
    o += (bytes + 255) & ~(size_t)255;
    return r;
  };
  __hip_bfloat16* wmix = (__hip_bfloat16*)(ws + alloc((size_t)DD * DD * 2));
  __hip_bfloat16* wzht = (__hip_bfloat16*)(ws + alloc((size_t)2 * DD * DD * 2));
  __hip_bfloat16* wpqT = (__hip_bfloat16*)(ws + alloc((size_t)DD * DD * 2));  // projq^T
  __hip_bfloat16* wsk  = (__hip_bfloat16*)(ws + alloc((size_t)SS * DD * 2));
  __hip_bfloat16* wpo  = (__hip_bfloat16*)(ws + alloc((size_t)DD * DD * 2));
  __hip_bfloat16* wfu  = (__hip_bfloat16*)(ws + alloc((size_t)2 * FF * DD * 2));  // gate/up interleaved
  __hip_bfloat16* wd   = (__hip_bfloat16*)(ws + alloc((size_t)DD * FF * 2));
  __hip_bfloat16* w2b  = (__hip_bfloat16*)(ws + alloc((size_t)SS * DD * 2));  // slot_keys @ projq
  float* wcomb = (float*)(ws + alloc((size_t)DD * 16 * 4));
  float* xws   = (float*)(ws + alloc((size_t)MTOK * DD * 4));
  __hip_bfloat16* xnb  = (__hip_bfloat16*)(ws + alloc((size_t)MTOK * DD * 2));
  __hip_bfloat16* retr = (__hip_bfloat16*)(ws + alloc((size_t)MTOK * DD * 2));
  float* scanA  = (float*)(ws + alloc((size_t)BB * NCHUNK * DD * 4));
  float* scanB  = (float*)(ws + alloc((size_t)BB * NCHUNK * DD * 4));
  float* hstart = (float*)(ws + alloc((size_t)BB * NCHUNK * DD * 4));
  char* big = ws + alloc((size_t)MTOK * FF * 4);  // 134 MB shared region
  // aliases (lifetimes disjoint):
  __hip_bfloat16* xn1b  = (__hip_bfloat16*)big;                            // phase 1
  __hip_bfloat16* convb = (__hip_bfloat16*)(big + (size_t)MTOK * DD * 2);  // phase 1
  __hip_bfloat16* zhtb  = (__hip_bfloat16*)big;                            // phase 2
  float* candf          = (float*)big;                                     // phase 3 (4 MB)
  __hip_bfloat16* ffin  = (__hip_bfloat16*)big;                            // phase 4
  float* Pbuf           = (float*)(big + (size_t)MTOK * FF * 2);           // phase 4 (2x33.5MB)

  // weight conversions — one batched dispatch
  {
    CvtArgs a;
    const float* srcs[9] = {mixw, wzw, whw, pqw, slotk, pow_, gatew, upw, downw};
    __hip_bfloat16* dsts[9] = {wmix, wzht, wzht + (size_t)DD * DD, wpqT, wsk, wpo, wfu, wfu, wd};
    int n4s[9] = {DD * DD / 4, DD * DD / 4, DD * DD / 4, DD * DD / 4, SS * DD / 4,
                  DD * DD / 4, FF * DD / 4, FF * DD / 4, DD * FF / 4};
    int modes[9] = {0, 0, 0, 3, 0, 0, 1, 2, 0};
    int acc_ = 0;
    for (int i = 0; i < 9; i++) {
      a.src[i] = srcs[i]; a.dst[i] = dsts[i]; a.off4[i] = acc_; a.mode[i] = modes[i];
      acc_ += n4s[i];
    }
    a.off4[9] = acc_;
    cvt_all_kernel<<<(acc_ + 255) / 256, 256, 0, stream>>>(a);
  }
  wcomb_kernel<<<DD / 256, 256, 0, stream>>>(w3, w7, w15, wcomb);
  // fold projq into slot_keys: W2[S,D] = slot_keys @ projq  (B = projq^T)
  gemm_bt<2, 1, 0><<<dim3(DD / 128, SS / 128), 256, 0, stream>>>(
      wsk, wpqT, SS, DD, DD, nullptr, w2b, nullptr, nullptr);

  // 1. conv block
  rms_kernel<<<MTOK, 256, 0, stream>>>(x_in, n1w, xn1b);
  conv_kernel<<<dim3(TT / 64, DD / 64, BB), 256, 0, stream>>>(xn1b, wcomb, convb);
  gemm_bt64<0><<<dim3(DD / 128, MTOK / 64), 256, 0, stream>>>(
      convb, wmix, MTOK, DD, DD, x_in, xws, nullptr);

  // 2. MinGRU
  rms_kernel<<<MTOK, 256, 0, stream>>>(xws, n2w, xnb);
  gemm_bt<1, 1, 0><<<dim3(2048 / 128, MTOK / 128), 256, 0, stream>>>(
      xnb, wzht, MTOK, 2048, DD, nullptr, zhtb, wzb, whb);
  scan_pass1<<<dim3(DD / 256, NCHUNK, BB), 256, 0, stream>>>(zhtb, scanA, scanB);
  scan_pass2<<<dim3(DD / 256, BB), 256, 0, stream>>>(h_prev, scanA, scanB, hstart,
                                                     out + (size_t)MTOK * DD);
  scan_pass3<<<dim3(DD / 256, NCHUNK, BB), 256, 0, stream>>>(zhtb, hstart, xws);

  // 3. slot memory (scores = xn @ W2^T directly; top-2 fused into epilogue)
  rms_kernel<<<MTOK, 256, 0, stream>>>(xws, n3w, xnb);
  gemm_bt<8, 1, 1><<<dim3(SS / 128, MTOK / 128), 256, 0, stream>>>(
      xnb, w2b, MTOK, SS, DD, candf, nullptr, nullptr, nullptr);
  topk_merge<<<MTOK / 4, 256, 0, stream>>>((const float4*)candf, slotv, retr);
  gemm_bt64<0><<<dim3(DD / 128, MTOK / 64), 256, 0, stream>>>(
      retr, wpo, MTOK, DD, DD, xws, xws, nullptr);

  // 4. SwiGLU FFN (fused gate+up, then split-K down + reduce)
  rms_kernel<<<MTOK, 256, 0, stream>>>(xws, n4w, xnb);
  gemm_bt<7, 1, 1><<<dim3(2 * FF / 128, MTOK / 128), 256, 0, stream>>>(
      xnb, wfu, MTOK, 2 * FF, DD, nullptr, ffin, nullptr, nullptr);
  gemm_bt<6, 2, 0><<<dim3(DD / 128, MTOK / 128, 2), 256, 0, stream>>>(
      ffin, wd, MTOK, DD, FF, Pbuf, nullptr, nullptr, nullptr);
  reduce_down<<<MTOK * DD / 1024, 256, 0, stream>>>(Pbuf, xws, out);
}

// Round 6
// 759.489 us; speedup vs baseline: 1.0714x; 1.0472x over previous
//
#include <hip/hip_runtime.h>
#include <hip/hip_bf16.h>
#include <cstdint>
#include <cfloat>
#include <climits>

// Problem constants (setup_inputs: B=2, T=4096, D=1024, F=4096, S=4096)
#define BB   2
#define TT   4096
#define DD   1024
#define FF   4096
#define SS   4096
#define MTOK (BB * TT)   // 8192 tokens
#define NCHUNK 32
#define TCHUNK 128

typedef __bf16 bf16x8 __attribute__((ext_vector_type(8)));
typedef float  f32x4  __attribute__((ext_vector_type(4)));
typedef __attribute__((address_space(3))) char lds_char;
typedef __attribute__((address_space(1))) char g_char;

// top-2 merge with (value desc, index asc) total order — exact jax top_k tie
// semantics. Merges (w0,j0,w1,j1) into (v0,i0,v1,i1).
#define TKMERGE(w0, j0, w1, j1)                                              \
  {                                                                          \
    if (w0 > v0 || (w0 == v0 && j0 < i0)) {                                  \
      float t0v = v0; int t0i = i0; v0 = w0; i0 = j0;                        \
      if (t0v > w1 || (t0v == w1 && t0i < j1)) { v1 = t0v; i1 = t0i; }       \
      else { v1 = w1; i1 = j1; }                                             \
    } else {                                                                 \
      if (w0 > v1 || (w0 == v1 && j0 < i1)) { v1 = w0; i1 = j0; }            \
    }                                                                        \
  }

// ---------------------------------------------------------------------------
// batched fp32 -> bf16 convert for all 9 weight matrices in one dispatch.
// mode 0: linear copy. mode 1/2: gate/up row interleave for the fused FFN.
// mode 3: 1024x1024 transpose (for projq^T, consumed as GEMM B operand).
// ---------------------------------------------------------------------------
struct CvtArgs {
  const float* src[9];
  __hip_bfloat16* dst[9];
  int off4[10];  // prefix sums of float4 counts
  int mode[9];
};

__global__ __launch_bounds__(256) void cvt_all_kernel(CvtArgs a) {
  int g = blockIdx.x * 256 + threadIdx.x;
  if (g >= a.off4[9]) return;
  int s = 0;
  while (g >= a.off4[s + 1]) s++;
  int i = g - a.off4[s];
  float4 v = ((const float4*)a.src[s])[i];
  union { ushort4 u; __hip_bfloat16 h[4]; } p;
  p.h[0] = __float2bfloat16(v.x);
  p.h[1] = __float2bfloat16(v.y);
  p.h[2] = __float2bfloat16(v.z);
  p.h[3] = __float2bfloat16(v.w);
  int m = a.mode[s];
  if (m == 3) {
    int r = i >> 8, c4 = i & 255;
#pragma unroll
    for (int k = 0; k < 4; k++)
      a.dst[s][(size_t)(c4 * 4 + k) * 1024 + r] = p.h[k];
    return;
  }
  int di = i;
  if (m == 1 || m == 2) {
    int r = i >> 8, c = i & 255;
    int dr = ((r >> 4) << 5) + (r & 15) + ((m == 2) ? 16 : 0);
    di = (dr << 8) + c;
  }
  ((ushort4*)a.dst[s])[di] = p.u;
}

// ---------------------------------------------------------------------------
// combine the 3 causal depthwise kernels into one 15-tap (padded to 16) table
// ---------------------------------------------------------------------------
__global__ void wcomb_kernel(const float* __restrict__ w3, const float* __restrict__ w7,
                             const float* __restrict__ w15, float* __restrict__ wc) {
  int d = blockIdx.x * 256 + threadIdx.x;
  if (d >= DD) return;
  for (int j = 0; j < 16; j++) {
    float v = 0.f;
    if (j < 15) {
      v = w15[d * 15 + (14 - j)];
      if (j < 7) v += w7[d * 7 + (6 - j)];
      if (j < 3) v += w3[d * 3 + (2 - j)];
    }
    wc[d * 16 + j] = v;
  }
}

// ---------------------------------------------------------------------------
// RMSNorm: one block per row of 1024, fp32 or bf16 in, bf16 out
// ---------------------------------------------------------------------------
template <int INBF16>
__global__ __launch_bounds__(256) void rms_kernel(const void* __restrict__ xv,
                                                  const float* __restrict__ w,
                                                  __hip_bfloat16* __restrict__ ob) {
  const int row = blockIdx.x;
  const int tid = threadIdx.x;
  float4 v;
  if constexpr (INBF16) {
    union { ushort4 u; __hip_bfloat16 h[4]; } q;
    q.u = ((const ushort4*)((const __hip_bfloat16*)xv + (size_t)row * DD))[tid];
    v.x = __bfloat162float(q.h[0]); v.y = __bfloat162float(q.h[1]);
    v.z = __bfloat162float(q.h[2]); v.w = __bfloat162float(q.h[3]);
  } else {
    v = ((const float4*)((const float*)xv + (size_t)row * DD))[tid];
  }
  float ss = v.x * v.x + v.y * v.y + v.z * v.z + v.w * v.w;
  for (int off = 32; off > 0; off >>= 1) ss += __shfl_down(ss, off, 64);
  __shared__ float wsum[4];
  if ((tid & 63) == 0) wsum[tid >> 6] = ss;
  __syncthreads();
  float tot = wsum[0] + wsum[1] + wsum[2] + wsum[3];
  float rinv = 1.0f / sqrtf(tot * (1.0f / DD) + 1e-6f);
  float4 wg = ((const float4*)w)[tid];
  union { ushort4 u; __hip_bfloat16 h[4]; } p;
  p.h[0] = __float2bfloat16(v.x * wg.x * rinv);
  p.h[1] = __float2bfloat16(v.y * wg.y * rinv);
  p.h[2] = __float2bfloat16(v.z * wg.z * rinv);
  p.h[3] = __float2bfloat16(v.w * wg.w * rinv);
  ((ushort4*)ob)[(size_t)row * 256 + tid] = p.u;
}

// ---------------------------------------------------------------------------
// multi-scale causal depthwise conv, 15 taps combined, LDS tiled with halo
// ---------------------------------------------------------------------------
__global__ __launch_bounds__(256) void conv_kernel(const __hip_bfloat16* __restrict__ xn,
                                                   const float* __restrict__ wc,
                                                   __hip_bfloat16* __restrict__ outp) {
  __shared__ float xt[78][64];
  __shared__ float wt[64][15];
  const int b = blockIdx.z, t0 = blockIdx.x * 64, d0 = blockIdx.y * 64;
  const int tid = threadIdx.x;
  const int dl = tid & 63;
  for (int idx = tid; idx < 64 * 15; idx += 256) {
    int d = idx / 15, j = idx % 15;
    wt[d][j] = wc[(d0 + d) * 16 + j];
  }
  for (int r = tid >> 6; r < 78; r += 4) {
    int t = t0 - 14 + r;
    xt[r][dl] = (t >= 0) ? __bfloat162float(xn[((size_t)b * TT + t) * DD + d0 + dl]) : 0.f;
  }
  __syncthreads();
  for (int tl = tid >> 6; tl < 64; tl += 4) {
    float acc = 0.f;
#pragma unroll
    for (int j = 0; j < 15; j++) acc += wt[dl][j] * xt[tl + 14 - j][dl];
    outp[((size_t)b * TT + t0 + tl) * DD + d0 + dl] = __float2bfloat16(acc);
  }
}

// ---------------------------------------------------------------------------
// bf16 GEMM, C[M,N] = A[M,K] @ B[N,K]^T, m97 structure, 128x128 tile, BK=32.
// SWZ 0: m-sliced XCD swizzle — use when B per XCD fits L2.
// SWZ 1: weight-stationary N-sliced swizzle — for large-N weight GEMMs.
// Epilogues:
//  1: z/htilde: bias + sigmoid on cols<1024, bf16 out (N=2048)
//  2: outb = bf16(acc)
//  6: split-K bf16 partial: outb[z*M*N + idx] = bf16(acc)
//  7: fused FFN: j-even tile = gate, j-odd = up; outb = bf16(silu(g)*u)
//  8: scores top-2 candidates -> outf float4 {v0, v1, bits(i0), bits(i1)}
// ---------------------------------------------------------------------------
template <int EPI, int KSPLIT = 1, int SWZ = 0>
__global__ __launch_bounds__(256, 2) void gemm_bt(
    const __hip_bfloat16* __restrict__ A, const __hip_bfloat16* __restrict__ Bm,
    const int M, const int N, const int K,
    float* __restrict__ outf, __hip_bfloat16* __restrict__ outb,
    const float* __restrict__ bias0, const float* __restrict__ bias1) {
  __shared__ __align__(16) __hip_bfloat16 As[128 * 32];
  __shared__ __align__(16) __hip_bfloat16 Bs[128 * 32];
  const int tid = threadIdx.x;
  const int lane = tid & 63;
  const int wave = tid >> 6;
  const int fm = lane & 15, fq = lane >> 4;

  const int nT = gridDim.x;
  const int lin = blockIdx.y * nT + blockIdx.x;
  int tileM, tileN;
  if constexpr (SWZ == 0) {
    const int xcd = lin & 7;
    const int idx_ = lin >> 3;
    const int mq = idx_ / nT;
    tileM = (xcd * (gridDim.y >> 3) + mq) * 128;
    tileN = (idx_ - mq * nT) * 128;
  } else {
    const int xcd = lin & 7;
    const int idx_ = lin >> 3;
    const int nS = nT >> 3;
    const int m = idx_ / nS;
    const int nl = idx_ - m * nS;
    tileM = m * 128;
    tileN = (xcd * nS + nl) * 128;
  }

  const int wm = (wave & 1) * 64, wn = (wave >> 1) * 64;

  f32x4 acc[4][4] = {};

  const int srow = tid >> 2;
  const int scol = (tid & 3) * 8;
  const __hip_bfloat16* gA = A + (size_t)(tileM + srow) * K + scol;
  const __hip_bfloat16* gB = Bm + (size_t)(tileN + srow) * K + scol;
  lds_char* ldsA = (lds_char*)(&As[0]);
  lds_char* ldsB = (lds_char*)(&Bs[0]);
  const int wbyte = wave * 1024;

  const int kPer = K / KSPLIT;
  const int kBeg = (KSPLIT > 1) ? blockIdx.z * kPer : 0;
  for (int k0 = kBeg; k0 < kBeg + kPer; k0 += 32) {
    __syncthreads();
    __builtin_amdgcn_global_load_lds((g_char*)(void*)(gA + k0),                  ldsA + wbyte,        16, 0, 0);
    __builtin_amdgcn_global_load_lds((g_char*)(void*)(gA + k0 + (size_t)64 * K), ldsA + wbyte + 4096, 16, 0, 0);
    __builtin_amdgcn_global_load_lds((g_char*)(void*)(gB + k0),                  ldsB + wbyte,        16, 0, 0);
    __builtin_amdgcn_global_load_lds((g_char*)(void*)(gB + k0 + (size_t)64 * K), ldsB + wbyte + 4096, 16, 0, 0);
    __syncthreads();
    bf16x8 af[4], bfr[4];
#pragma unroll
    for (int i = 0; i < 4; i++) {
      af[i]  = *(const bf16x8*)(As + (wm + i * 16 + fm) * 32 + fq * 8);
      bfr[i] = *(const bf16x8*)(Bs + (wn + i * 16 + fm) * 32 + fq * 8);
    }
#pragma unroll
    for (int i = 0; i < 4; i++)
#pragma unroll
      for (int j = 0; j < 4; j++)
        acc[i][j] = __builtin_amdgcn_mfma_f32_16x16x32_bf16(af[i], bfr[j], acc[i][j], 0, 0, 0);
  }

  // epilogue: C/D layout col = lane&15, row = (lane>>4)*4 + reg  [m89/m91]
  if constexpr (EPI == 7) {
#pragma unroll
    for (int i = 0; i < 4; i++) {
#pragma unroll
      for (int j = 0; j < 4; j += 2) {
        const int ffcol = (((tileN + wn + j * 16) >> 5) << 4) + fm;
#pragma unroll
        for (int r = 0; r < 4; r++) {
          const int rw = tileM + wm + i * 16 + fq * 4 + r;
          float g = acc[i][j][r];
          float u = acc[i][j + 1][r];
          float v = g / (1.f + __expf(-g)) * u;
          outb[(size_t)rw * FF + ffcol] = __float2bfloat16(v);
        }
      }
    }
  } else if constexpr (EPI == 8) {
    __shared__ float lv2[2][128][2];
    __shared__ int   li2[2][128][2];
    const int half = wn >> 6;
#pragma unroll
    for (int i = 0; i < 4; i++) {
#pragma unroll
      for (int r = 0; r < 4; r++) {
        float v0 = -FLT_MAX, v1 = -FLT_MAX;
        int i0 = INT_MAX, i1 = INT_MAX;
#pragma unroll
        for (int j = 0; j < 4; j++) {
          float v = acc[i][j][r];
          int c = tileN + wn + j * 16 + fm;
          if (v > v0) { v1 = v0; i1 = i0; v0 = v; i0 = c; }
          else if (v > v1) { v1 = v; i1 = c; }
        }
#pragma unroll
        for (int off = 1; off < 16; off <<= 1) {
          float w0 = __shfl_xor(v0, off, 64), w1 = __shfl_xor(v1, off, 64);
          int   j0 = __shfl_xor(i0, off, 64), j1 = __shfl_xor(i1, off, 64);
          TKMERGE(w0, j0, w1, j1);
        }
        if (fm == 0) {
          const int lrow = wm + i * 16 + fq * 4 + r;
          lv2[half][lrow][0] = v0; lv2[half][lrow][1] = v1;
          li2[half][lrow][0] = i0; li2[half][lrow][1] = i1;
        }
      }
    }
    __syncthreads();
    if (tid < 128) {
      float v0 = lv2[0][tid][0], v1 = lv2[0][tid][1];
      int   i0 = li2[0][tid][0], i1 = li2[0][tid][1];
      float w0 = lv2[1][tid][0], w1 = lv2[1][tid][1];
      int   j0 = li2[1][tid][0], j1 = li2[1][tid][1];
      TKMERGE(w0, j0, w1, j1);
      float4 c4;
      c4.x = v0; c4.y = v1;
      c4.z = __int_as_float(i0); c4.w = __int_as_float(i1);
      ((float4*)outf)[(size_t)(tileM + tid) * (SS / 128) + (tileN >> 7)] = c4;
    }
  } else {
#pragma unroll
    for (int i = 0; i < 4; i++) {
#pragma unroll
      for (int j = 0; j < 4; j++) {
        const int c = tileN + wn + j * 16 + fm;
#pragma unroll
        for (int r = 0; r < 4; r++) {
          const int rw = tileM + wm + i * 16 + fq * 4 + r;
          const size_t idx = (size_t)rw * N + c;
          float v = acc[i][j][r];
          if constexpr (EPI == 1) {
            v += (c < DD) ? bias0[c] : bias1[c - DD];
            if (c < DD) v = 1.f / (1.f + __expf(-v));
            outb[idx] = __float2bfloat16(v);
          } else if constexpr (EPI == 2) {
            outb[idx] = __float2bfloat16(v);
          } else if constexpr (EPI == 6) {
            outb[(size_t)blockIdx.z * M * N + idx] = __float2bfloat16(v);
          }
        }
      }
    }
  }
}

// ---------------------------------------------------------------------------
// 64x128 (MxN) tile variant for grid-limited N=1024 GEMMs (mix/projout).
// EPI 0: outb = bf16(residf_fp32 + acc);  EPI 3: outb = bf16(residb_bf16 + acc)
// ---------------------------------------------------------------------------
template <int EPI>
__global__ __launch_bounds__(256, 4) void gemm_bt64(
    const __hip_bfloat16* __restrict__ A, const __hip_bfloat16* __restrict__ Bm,
    const int M, const int N, const int K,
    const float* __restrict__ residf, const __hip_bfloat16* __restrict__ residb,
    __hip_bfloat16* __restrict__ outb) {
  __shared__ __align__(16) __hip_bfloat16 As[64 * 32];
  __shared__ __align__(16) __hip_bfloat16 Bs[128 * 32];
  const int tid = threadIdx.x;
  const int lane = tid & 63;
  const int wave = tid >> 6;
  const int fm = lane & 15, fq = lane >> 4;

  const int nT = gridDim.x;
  const int lin = blockIdx.y * nT + blockIdx.x;
  const int xcd = lin & 7;
  const int idx_ = lin >> 3;
  const int mq = idx_ / nT;
  const int tileM = (xcd * (gridDim.y >> 3) + mq) * 64;
  const int tileN = (idx_ - mq * nT) * 128;

  const int wm = (wave & 1) * 32, wn = (wave >> 1) * 64;

  f32x4 acc[2][4] = {};

  const int srow = tid >> 2;
  const int scol = (tid & 3) * 8;
  const __hip_bfloat16* gA = A + (size_t)(tileM + srow) * K + scol;
  const __hip_bfloat16* gB = Bm + (size_t)(tileN + srow) * K + scol;
  lds_char* ldsA = (lds_char*)(&As[0]);
  lds_char* ldsB = (lds_char*)(&Bs[0]);
  const int wbyte = wave * 1024;

  for (int k0 = 0; k0 < K; k0 += 32) {
    __syncthreads();
    __builtin_amdgcn_global_load_lds((g_char*)(void*)(gA + k0),                  ldsA + wbyte,        16, 0, 0);
    __builtin_amdgcn_global_load_lds((g_char*)(void*)(gB + k0),                  ldsB + wbyte,        16, 0, 0);
    __builtin_amdgcn_global_load_lds((g_char*)(void*)(gB + k0 + (size_t)64 * K), ldsB + wbyte + 4096, 16, 0, 0);
    __syncthreads();
    bf16x8 af[2], bfr[4];
#pragma unroll
    for (int i = 0; i < 2; i++)
      af[i]  = *(const bf16x8*)(As + (wm + i * 16 + fm) * 32 + fq * 8);
#pragma unroll
    for (int j = 0; j < 4; j++)
      bfr[j] = *(const bf16x8*)(Bs + (wn + j * 16 + fm) * 32 + fq * 8);
#pragma unroll
    for (int i = 0; i < 2; i++)
#pragma unroll
      for (int j = 0; j < 4; j++)
        acc[i][j] = __builtin_amdgcn_mfma_f32_16x16x32_bf16(af[i], bfr[j], acc[i][j], 0, 0, 0);
  }

#pragma unroll
  for (int i = 0; i < 2; i++) {
#pragma unroll
    for (int j = 0; j < 4; j++) {
      const int c = tileN + wn + j * 16 + fm;
#pragma unroll
      for (int r = 0; r < 4; r++) {
        const int rw = tileM + wm + i * 16 + fq * 4 + r;
        const size_t idx = (size_t)rw * N + c;
        float v = acc[i][j][r];
        if constexpr (EPI == 0) {
          outb[idx] = __float2bfloat16(residf[idx] + v);
        } else {
          outb[idx] = __float2bfloat16(__bfloat162float(residb[idx]) + v);
        }
      }
    }
  }
}

// ---------------------------------------------------------------------------
// split-K fixup for the down projection: out_fp32 = resid_bf16 + P0 + P1
// 8 elems/thread.
// ---------------------------------------------------------------------------
__global__ __launch_bounds__(256) void reduce_final(const __hip_bfloat16* __restrict__ P,
                                                    const __hip_bfloat16* __restrict__ resid,
                                                    float* __restrict__ out) {
  size_t i = (size_t)blockIdx.x * 256 + threadIdx.x;
  bf16x8 a = ((const bf16x8*)P)[i];
  bf16x8 b = ((const bf16x8*)(P + (size_t)MTOK * DD))[i];
  bf16x8 rr = ((const bf16x8*)resid)[i];
  float o[8];
#pragma unroll
  for (int k = 0; k < 8; k++)
    o[k] = (float)rr[k] + (float)a[k] + (float)b[k];
  float4 o0 = {o[0], o[1], o[2], o[3]};
  float4 o1 = {o[4], o[5], o[6], o[7]};
  ((float4*)out)[i * 2]     = o0;
  ((float4*)out)[i * 2 + 1] = o1;
}

// ---------------------------------------------------------------------------
// MinGRU chunked parallel scan over zht [MTOK, 2048] bf16 (z | htilde)
// ---------------------------------------------------------------------------
__global__ __launch_bounds__(256) void scan_pass1(const __hip_bfloat16* __restrict__ zht,
                                                  float* __restrict__ cA,
                                                  float* __restrict__ cB) {
  const int b = blockIdx.z, c = blockIdx.y;
  const int d = blockIdx.x * 256 + threadIdx.x;
  const __hip_bfloat16* base = zht + (size_t)b * TT * 2048;
  float A = 1.f, Bc = 0.f;
  const int t0 = c * TCHUNK;
  for (int t = t0; t < t0 + TCHUNK; t++) {
    const __hip_bfloat16* rowp = base + (size_t)t * 2048;
    float z = __bfloat162float(rowp[d]);
    float h = __bfloat162float(rowp[DD + d]);
    float om = 1.f - z;
    A *= om;
    Bc = om * Bc + z * h;
  }
  size_t idx = ((size_t)b * NCHUNK + c) * DD + d;
  cA[idx] = A;
  cB[idx] = Bc;
}

__global__ __launch_bounds__(256) void scan_pass2(const float* __restrict__ hp,
                                                  const float* __restrict__ cA,
                                                  const float* __restrict__ cB,
                                                  float* __restrict__ hstart,
                                                  float* __restrict__ hlast) {
  const int b = blockIdx.y;
  const int d = blockIdx.x * 256 + threadIdx.x;
  float h = hp[b * DD + d];
  for (int c = 0; c < NCHUNK; c++) {
    size_t idx = ((size_t)b * NCHUNK + c) * DD + d;
    hstart[idx] = h;
    h = cA[idx] * h + cB[idx];
  }
  hlast[b * DD + d] = h;
}

__global__ __launch_bounds__(256) void scan_pass3(const __hip_bfloat16* __restrict__ zht,
                                                  const float* __restrict__ hstart,
                                                  __hip_bfloat16* __restrict__ x) {
  const int b = blockIdx.z, c = blockIdx.y;
  const int d = blockIdx.x * 256 + threadIdx.x;
  const __hip_bfloat16* base = zht + (size_t)b * TT * 2048;
  float h = hstart[((size_t)b * NCHUNK + c) * DD + d];
  const int t0 = c * TCHUNK;
  for (int t = t0; t < t0 + TCHUNK; t++) {
    const __hip_bfloat16* rowp = base + (size_t)t * 2048;
    float z = __bfloat162float(rowp[d]);
    float ht = __bfloat162float(rowp[DD + d]);
    h = (1.f - z) * h + z * ht;
    size_t xi = ((size_t)b * TT + t) * DD + d;
    x[xi] = __float2bfloat16(__bfloat162float(x[xi]) + h);
  }
}

// ---------------------------------------------------------------------------
// merge 32 per-tile top-2 candidates per row -> global top-2, softmax, gather.
// One wave per row; 4 rows per block.
// ---------------------------------------------------------------------------
__global__ __launch_bounds__(256) void topk_merge(const float4* __restrict__ cand,
                                                  const float* __restrict__ sv,
                                                  __hip_bfloat16* __restrict__ ret) {
  const int row = blockIdx.x * 4 + (threadIdx.x >> 6);
  const int lane = threadIdx.x & 63;
  float v0 = -FLT_MAX, v1 = -FLT_MAX;
  int i0 = INT_MAX, i1 = INT_MAX;
  if (lane < 32) {
    float4 c = cand[(size_t)row * 32 + lane];
    v0 = c.x; v1 = c.y;
    i0 = __float_as_int(c.z); i1 = __float_as_int(c.w);
  }
#pragma unroll
  for (int off = 1; off < 64; off <<= 1) {
    float w0 = __shfl_xor(v0, off, 64), w1 = __shfl_xor(v1, off, 64);
    int   j0 = __shfl_xor(i0, off, 64), j1 = __shfl_xor(i1, off, 64);
    TKMERGE(w0, j0, w1, j1);
  }
  float s0 = v0 * (1.f / 32.f), s1 = v1 * (1.f / 32.f);  // /sqrt(D)
  float e = __expf(s1 - s0);
  float denom = 1.f + e;
  float a0 = 1.f / denom;
  float a1 = e / denom;
  const float4* r0 = (const float4*)(sv + (size_t)i0 * DD);
  const float4* r1 = (const float4*)(sv + (size_t)i1 * DD);
#pragma unroll
  for (int k = 0; k < 4; k++) {
    int j = lane + 64 * k;
    float4 u = r0[j], w4 = r1[j];
    union { ushort4 u; __hip_bfloat16 h[4]; } p;
    p.h[0] = __float2bfloat16(a0 * u.x + a1 * w4.x);
    p.h[1] = __float2bfloat16(a0 * u.y + a1 * w4.y);
    p.h[2] = __float2bfloat16(a0 * u.z + a1 * w4.z);
    p.h[3] = __float2bfloat16(a0 * u.w + a1 * w4.w);
    ((ushort4*)(ret + (size_t)row * DD))[j] = p.u;
  }
}

// ---------------------------------------------------------------------------
extern "C" void kernel_launch(void* const* d_in, const int* in_sizes, int n_in,
                              void* d_out, int out_size, void* d_ws, size_t ws_size,
                              hipStream_t stream) {
  (void)in_sizes; (void)n_in; (void)out_size; (void)ws_size;
  const float* x_in   = (const float*)d_in[0];
  const float* h_prev = (const float*)d_in[1];
  const float* n1w    = (const float*)d_in[2];
  const float* w3     = (const float*)d_in[3];
  const float* w7     = (const float*)d_in[4];
  const float* w15    = (const float*)d_in[5];
  const float* mixw   = (const float*)d_in[6];
  const float* n2w    = (const float*)d_in[7];
  const float* wzw    = (const float*)d_in[8];
  const float* wzb    = (const float*)d_in[9];
  const float* whw    = (const float*)d_in[10];
  const float* whb    = (const float*)d_in[11];
  const float* n3w    = (const float*)d_in[12];
  const float* slotk  = (const float*)d_in[13];
  const float* slotv  = (const float*)d_in[14];
  const float* pqw    = (const float*)d_in[15];
  const float* pow_   = (const float*)d_in[16];
  const float* n4w    = (const float*)d_in[17];
  const float* gatew  = (const float*)d_in[18];
  const float* upw    = (const float*)d_in[19];
  const float* downw  = (const float*)d_in[20];
  float* out = (float*)d_out;

  char* ws = (char*)d_ws;
  size_t o = 0;
  auto alloc = [&](size_t bytes) {
    size_t r = o;
    o += (bytes + 255) & ~(size_t)255;
    return r;
  };
  __hip_bfloat16* wmix = (__hip_bfloat16*)(ws + alloc((size_t)DD * DD * 2));
  __hip_bfloat16* wzht = (__hip_bfloat16*)(ws + alloc((size_t)2 * DD * DD * 2));
  __hip_bfloat16* wpqT = (__hip_bfloat16*)(ws + alloc((size_t)DD * DD * 2));  // projq^T
  __hip_bfloat16* wsk  = (__hip_bfloat16*)(ws + alloc((size_t)SS * DD * 2));
  __hip_bfloat16* wpo  = (__hip_bfloat16*)(ws + alloc((size_t)DD * DD * 2));
  __hip_bfloat16* wfu  = (__hip_bfloat16*)(ws + alloc((size_t)2 * FF * DD * 2));  // gate/up interleaved
  __hip_bfloat16* wd   = (__hip_bfloat16*)(ws + alloc((size_t)DD * FF * 2));
  __hip_bfloat16* w2b  = (__hip_bfloat16*)(ws + alloc((size_t)SS * DD * 2));  // slot_keys @ projq
  float* wcomb = (float*)(ws + alloc((size_t)DD * 16 * 4));
  __hip_bfloat16* xws  = (__hip_bfloat16*)(ws + alloc((size_t)MTOK * DD * 2));  // bf16 residual stream
  __hip_bfloat16* xnb  = (__hip_bfloat16*)(ws + alloc((size_t)MTOK * DD * 2));
  __hip_bfloat16* retr = (__hip_bfloat16*)(ws + alloc((size_t)MTOK * DD * 2));
  float* scanA  = (float*)(ws + alloc((size_t)BB * NCHUNK * DD * 4));
  float* scanB  = (float*)(ws + alloc((size_t)BB * NCHUNK * DD * 4));
  float* hstart = (float*)(ws + alloc((size_t)BB * NCHUNK * DD * 4));
  char* big = ws + alloc((size_t)MTOK * FF * 4);  // 134 MB shared region
  // aliases (lifetimes disjoint):
  __hip_bfloat16* xn1b  = (__hip_bfloat16*)big;                            // phase 1
  __hip_bfloat16* convb = (__hip_bfloat16*)(big + (size_t)MTOK * DD * 2);  // phase 1
  __hip_bfloat16* zhtb  = (__hip_bfloat16*)big;                            // phase 2
  float* candf          = (float*)big;                                     // phase 3 (4 MB)
  __hip_bfloat16* ffin  = (__hip_bfloat16*)big;                            // phase 4
  __hip_bfloat16* Pbuf  = (__hip_bfloat16*)(big + (size_t)MTOK * FF * 2);  // phase 4 (2x16.7MB bf16)

  // weight conversions — one batched dispatch
  {
    CvtArgs a;
    const float* srcs[9] = {mixw, wzw, whw, pqw, slotk, pow_, gatew, upw, downw};
    __hip_bfloat16* dsts[9] = {wmix, wzht, wzht + (size_t)DD * DD, wpqT, wsk, wpo, wfu, wfu, wd};
    int n4s[9] = {DD * DD / 4, DD * DD / 4, DD * DD / 4, DD * DD / 4, SS * DD / 4,
                  DD * DD / 4, FF * DD / 4, FF * DD / 4, DD * FF / 4};
    int modes[9] = {0, 0, 0, 3, 0, 0, 1, 2, 0};
    int acc_ = 0;
    for (int i = 0; i < 9; i++) {
      a.src[i] = srcs[i]; a.dst[i] = dsts[i]; a.off4[i] = acc_; a.mode[i] = modes[i];
      acc_ += n4s[i];
    }
    a.off4[9] = acc_;
    cvt_all_kernel<<<(acc_ + 255) / 256, 256, 0, stream>>>(a);
  }
  wcomb_kernel<<<DD / 256, 256, 0, stream>>>(w3, w7, w15, wcomb);
  // fold projq into slot_keys: W2[S,D] = slot_keys @ projq  (B = projq^T)
  gemm_bt<2, 1, 0><<<dim3(DD / 128, SS / 128), 256, 0, stream>>>(
      wsk, wpqT, SS, DD, DD, nullptr, w2b, nullptr, nullptr);

  // 1. conv block
  rms_kernel<0><<<MTOK, 256, 0, stream>>>(x_in, n1w, xn1b);
  conv_kernel<<<dim3(TT / 64, DD / 64, BB), 256, 0, stream>>>(xn1b, wcomb, convb);
  gemm_bt64<0><<<dim3(DD / 128, MTOK / 64), 256, 0, stream>>>(
      convb, wmix, MTOK, DD, DD, x_in, nullptr, xws);

  // 2. MinGRU
  rms_kernel<1><<<MTOK, 256, 0, stream>>>(xws, n2w, xnb);
  gemm_bt<1, 1, 0><<<dim3(2048 / 128, MTOK / 128), 256, 0, stream>>>(
      xnb, wzht, MTOK, 2048, DD, nullptr, zhtb, wzb, whb);
  scan_pass1<<<dim3(DD / 256, NCHUNK, BB), 256, 0, stream>>>(zhtb, scanA, scanB);
  scan_pass2<<<dim3(DD / 256, BB), 256, 0, stream>>>(h_prev, scanA, scanB, hstart,
                                                     out + (size_t)MTOK * DD);
  scan_pass3<<<dim3(DD / 256, NCHUNK, BB), 256, 0, stream>>>(zhtb, hstart, xws);

  // 3. slot memory (scores = xn @ W2^T directly; top-2 fused into epilogue)
  rms_kernel<1><<<MTOK, 256, 0, stream>>>(xws, n3w, xnb);
  gemm_bt<8, 1, 1><<<dim3(SS / 128, MTOK / 128), 256, 0, stream>>>(
      xnb, w2b, MTOK, SS, DD, candf, nullptr, nullptr, nullptr);
  topk_merge<<<MTOK / 4, 256, 0, stream>>>((const float4*)candf, slotv, retr);
  gemm_bt64<3><<<dim3(DD / 128, MTOK / 64), 256, 0, stream>>>(
      retr, wpo, MTOK, DD, DD, nullptr, xws, xws);

  // 4. SwiGLU FFN (fused gate+up, then split-K down + reduce)
  rms_kernel<1><<<MTOK, 256, 0, stream>>>(xws, n4w, xnb);
  gemm_bt<7, 1, 1><<<dim3(2 * FF / 128, MTOK / 128), 256, 0, stream>>>(
      xnb, wfu, MTOK, 2 * FF, DD, nullptr, ffin, nullptr, nullptr);
  gemm_bt<6, 2, 0><<<dim3(DD / 128, MTOK / 128, 2), 256, 0, stream>>>(
      ffin, wd, MTOK, DD, FF, nullptr, Pbuf, nullptr, nullptr);
  reduce_final<<<MTOK * DD / 2048, 256, 0, stream>>>(Pbuf, xws, out);
}

// Round 7
// 741.877 us; speedup vs baseline: 1.0968x; 1.0237x over previous
//
#include <hip/hip_runtime.h>
#include <hip/hip_bf16.h>
#include <cstdint>
#include <cfloat>
#include <climits>

// Problem constants (setup_inputs: B=2, T=4096, D=1024, F=4096, S=4096)
#define BB   2
#define TT   4096
#define DD   1024
#define FF   4096
#define SS   4096
#define MTOK (BB * TT)   // 8192 tokens
#define NCHUNK 32
#define TCHUNK 128

typedef __bf16 bf16x8 __attribute__((ext_vector_type(8)));
typedef float  f32x4  __attribute__((ext_vector_type(4)));
typedef __attribute__((address_space(3))) char lds_char;
typedef __attribute__((address_space(1))) char g_char;

// top-2 merge with (value desc, index asc) total order — exact jax top_k tie
// semantics. Merges (w0,j0,w1,j1) into (v0,i0,v1,i1).
#define TKMERGE(w0, j0, w1, j1)                                              \
  {                                                                          \
    if (w0 > v0 || (w0 == v0 && j0 < i0)) {                                  \
      float t0v = v0; int t0i = i0; v0 = w0; i0 = j0;                        \
      if (t0v > w1 || (t0v == w1 && t0i < j1)) { v1 = t0v; i1 = t0i; }       \
      else { v1 = w1; i1 = j1; }                                             \
    } else {                                                                 \
      if (w0 > v1 || (w0 == v1 && j0 < i1)) { v1 = w0; i1 = j0; }            \
    }                                                                        \
  }

// ---------------------------------------------------------------------------
// batched fp32 -> bf16 convert for all 10 weight matrices in one dispatch.
// mode 0: linear copy. mode 1/2: gate/up row interleave for the fused FFN.
// mode 3: 1024x1024 transpose (for projq^T, consumed as GEMM B operand).
// ---------------------------------------------------------------------------
struct CvtArgs {
  const float* src[10];
  __hip_bfloat16* dst[10];
  int off4[11];  // prefix sums of float4 counts
  int mode[10];
};

__global__ __launch_bounds__(256) void cvt_all_kernel(CvtArgs a) {
  int g = blockIdx.x * 256 + threadIdx.x;
  if (g >= a.off4[10]) return;
  int s = 0;
  while (g >= a.off4[s + 1]) s++;
  int i = g - a.off4[s];
  float4 v = ((const float4*)a.src[s])[i];
  union { ushort4 u; __hip_bfloat16 h[4]; } p;
  p.h[0] = __float2bfloat16(v.x);
  p.h[1] = __float2bfloat16(v.y);
  p.h[2] = __float2bfloat16(v.z);
  p.h[3] = __float2bfloat16(v.w);
  int m = a.mode[s];
  if (m == 3) {
    int r = i >> 8, c4 = i & 255;
#pragma unroll
    for (int k = 0; k < 4; k++)
      a.dst[s][(size_t)(c4 * 4 + k) * 1024 + r] = p.h[k];
    return;
  }
  int di = i;
  if (m == 1 || m == 2) {
    int r = i >> 8, c = i & 255;
    int dr = ((r >> 4) << 5) + (r & 15) + ((m == 2) ? 16 : 0);
    di = (dr << 8) + c;
  }
  ((ushort4*)a.dst[s])[di] = p.u;
}

// ---------------------------------------------------------------------------
// combine the 3 causal depthwise kernels into one 15-tap (padded to 16) table
// ---------------------------------------------------------------------------
__global__ void wcomb_kernel(const float* __restrict__ w3, const float* __restrict__ w7,
                             const float* __restrict__ w15, float* __restrict__ wc) {
  int d = blockIdx.x * 256 + threadIdx.x;
  if (d >= DD) return;
  for (int j = 0; j < 16; j++) {
    float v = 0.f;
    if (j < 15) {
      v = w15[d * 15 + (14 - j)];
      if (j < 7) v += w7[d * 7 + (6 - j)];
      if (j < 3) v += w3[d * 3 + (2 - j)];
    }
    wc[d * 16 + j] = v;
  }
}

// ---------------------------------------------------------------------------
// RMSNorm: one block per row of 1024, fp32 or bf16 in, bf16 out
// ---------------------------------------------------------------------------
template <int INBF16>
__global__ __launch_bounds__(256) void rms_kernel(const void* __restrict__ xv,
                                                  const float* __restrict__ w,
                                                  __hip_bfloat16* __restrict__ ob) {
  const int row = blockIdx.x;
  const int tid = threadIdx.x;
  float4 v;
  if constexpr (INBF16) {
    union { ushort4 u; __hip_bfloat16 h[4]; } q;
    q.u = ((const ushort4*)((const __hip_bfloat16*)xv + (size_t)row * DD))[tid];
    v.x = __bfloat162float(q.h[0]); v.y = __bfloat162float(q.h[1]);
    v.z = __bfloat162float(q.h[2]); v.w = __bfloat162float(q.h[3]);
  } else {
    v = ((const float4*)((const float*)xv + (size_t)row * DD))[tid];
  }
  float ss = v.x * v.x + v.y * v.y + v.z * v.z + v.w * v.w;
  for (int off = 32; off > 0; off >>= 1) ss += __shfl_down(ss, off, 64);
  __shared__ float wsum[4];
  if ((tid & 63) == 0) wsum[tid >> 6] = ss;
  __syncthreads();
  float tot = wsum[0] + wsum[1] + wsum[2] + wsum[3];
  float rinv = 1.0f / sqrtf(tot * (1.0f / DD) + 1e-6f);
  float4 wg = ((const float4*)w)[tid];
  union { ushort4 u; __hip_bfloat16 h[4]; } p;
  p.h[0] = __float2bfloat16(v.x * wg.x * rinv);
  p.h[1] = __float2bfloat16(v.y * wg.y * rinv);
  p.h[2] = __float2bfloat16(v.z * wg.z * rinv);
  p.h[3] = __float2bfloat16(v.w * wg.w * rinv);
  ((ushort4*)ob)[(size_t)row * 256 + tid] = p.u;
}

// ---------------------------------------------------------------------------
// multi-scale causal depthwise conv, 15 taps combined, LDS tiled with halo
// ---------------------------------------------------------------------------
__global__ __launch_bounds__(256) void conv_kernel(const __hip_bfloat16* __restrict__ xn,
                                                   const float* __restrict__ wc,
                                                   __hip_bfloat16* __restrict__ outp) {
  __shared__ float xt[78][64];
  __shared__ float wt[64][15];
  const int b = blockIdx.z, t0 = blockIdx.x * 64, d0 = blockIdx.y * 64;
  const int tid = threadIdx.x;
  const int dl = tid & 63;
  for (int idx = tid; idx < 64 * 15; idx += 256) {
    int d = idx / 15, j = idx % 15;
    wt[d][j] = wc[(d0 + d) * 16 + j];
  }
  for (int r = tid >> 6; r < 78; r += 4) {
    int t = t0 - 14 + r;
    xt[r][dl] = (t >= 0) ? __bfloat162float(xn[((size_t)b * TT + t) * DD + d0 + dl]) : 0.f;
  }
  __syncthreads();
  for (int tl = tid >> 6; tl < 64; tl += 4) {
    float acc = 0.f;
#pragma unroll
    for (int j = 0; j < 15; j++) acc += wt[dl][j] * xt[tl + 14 - j][dl];
    outp[((size_t)b * TT + t0 + tl) * DD + d0 + dl] = __float2bfloat16(acc);
  }
}

// ---------------------------------------------------------------------------
// bf16 GEMM, C[M,N] = A[M,K] @ B[N,K]^T. m97 structure + dual-panel K-loop:
// two BK=32 LDS panels staged per barrier-pair (32 MFMA per barrier drain
// instead of 16 — AITER-style amortization; LDS 32 KB, occupancy unchanged
// since VGPR/waves bind first). Requires K % 64 == 0.
// SWZ 0: m-sliced XCD swizzle — use when B per XCD fits L2.
// SWZ 1: weight-stationary N-sliced swizzle — for large-N weight GEMMs.
// Epilogues:
//  1: z/htilde: bias + sigmoid on cols<1024, bf16 out (N=2048)
//  2: outb = bf16(acc)
//  6: split-K bf16 partial: outb[z*M*N + idx] = bf16(acc)
//  7: fused FFN: j-even tile = gate, j-odd = up; outb = bf16(silu(g)*u)
//  8: scores top-2 candidates -> outf float4 {v0, v1, bits(i0), bits(i1)}
// ---------------------------------------------------------------------------
template <int EPI, int KSPLIT = 1, int SWZ = 0>
__global__ __launch_bounds__(256, 2) void gemm_bt(
    const __hip_bfloat16* __restrict__ A, const __hip_bfloat16* __restrict__ Bm,
    const int M, const int N, const int K,
    float* __restrict__ outf, __hip_bfloat16* __restrict__ outb,
    const float* __restrict__ bias0, const float* __restrict__ bias1) {
  __shared__ __align__(16) __hip_bfloat16 As[2][128 * 32];
  __shared__ __align__(16) __hip_bfloat16 Bs[2][128 * 32];
  const int tid = threadIdx.x;
  const int lane = tid & 63;
  const int wave = tid >> 6;
  const int fm = lane & 15, fq = lane >> 4;

  const int nT = gridDim.x;
  const int lin = blockIdx.y * nT + blockIdx.x;
  int tileM, tileN;
  if constexpr (SWZ == 0) {
    const int xcd = lin & 7;
    const int idx_ = lin >> 3;
    const int mq = idx_ / nT;
    tileM = (xcd * (gridDim.y >> 3) + mq) * 128;
    tileN = (idx_ - mq * nT) * 128;
  } else {
    const int xcd = lin & 7;
    const int idx_ = lin >> 3;
    const int nS = nT >> 3;
    const int m = idx_ / nS;
    const int nl = idx_ - m * nS;
    tileM = m * 128;
    tileN = (xcd * nS + nl) * 128;
  }

  const int wm = (wave & 1) * 64, wn = (wave >> 1) * 64;

  f32x4 acc[4][4] = {};

  const int srow = tid >> 2;
  const int scol = (tid & 3) * 8;
  const __hip_bfloat16* gA = A + (size_t)(tileM + srow) * K + scol;
  const __hip_bfloat16* gB = Bm + (size_t)(tileN + srow) * K + scol;
  lds_char* ldsA0 = (lds_char*)(&As[0][0]);
  lds_char* ldsA1 = (lds_char*)(&As[1][0]);
  lds_char* ldsB0 = (lds_char*)(&Bs[0][0]);
  lds_char* ldsB1 = (lds_char*)(&Bs[1][0]);
  const int wbyte = wave * 1024;

  const int kPer = K / KSPLIT;
  const int kBeg = (KSPLIT > 1) ? blockIdx.z * kPer : 0;
  for (int k0 = kBeg; k0 < kBeg + kPer; k0 += 64) {
    __syncthreads();
    __builtin_amdgcn_global_load_lds((g_char*)(void*)(gA + k0),                       ldsA0 + wbyte,        16, 0, 0);
    __builtin_amdgcn_global_load_lds((g_char*)(void*)(gA + k0 + (size_t)64 * K),      ldsA0 + wbyte + 4096, 16, 0, 0);
    __builtin_amdgcn_global_load_lds((g_char*)(void*)(gB + k0),                       ldsB0 + wbyte,        16, 0, 0);
    __builtin_amdgcn_global_load_lds((g_char*)(void*)(gB + k0 + (size_t)64 * K),      ldsB0 + wbyte + 4096, 16, 0, 0);
    __builtin_amdgcn_global_load_lds((g_char*)(void*)(gA + k0 + 32),                  ldsA1 + wbyte,        16, 0, 0);
    __builtin_amdgcn_global_load_lds((g_char*)(void*)(gA + k0 + 32 + (size_t)64 * K), ldsA1 + wbyte + 4096, 16, 0, 0);
    __builtin_amdgcn_global_load_lds((g_char*)(void*)(gB + k0 + 32),                  ldsB1 + wbyte,        16, 0, 0);
    __builtin_amdgcn_global_load_lds((g_char*)(void*)(gB + k0 + 32 + (size_t)64 * K), ldsB1 + wbyte + 4096, 16, 0, 0);
    __syncthreads();
#pragma unroll
    for (int s = 0; s < 2; s++) {
      bf16x8 af[4], bfr[4];
#pragma unroll
      for (int i = 0; i < 4; i++) {
        af[i]  = *(const bf16x8*)(&As[s][0] + (wm + i * 16 + fm) * 32 + fq * 8);
        bfr[i] = *(const bf16x8*)(&Bs[s][0] + (wn + i * 16 + fm) * 32 + fq * 8);
      }
#pragma unroll
      for (int i = 0; i < 4; i++)
#pragma unroll
        for (int j = 0; j < 4; j++)
          acc[i][j] = __builtin_amdgcn_mfma_f32_16x16x32_bf16(af[i], bfr[j], acc[i][j], 0, 0, 0);
    }
  }

  // epilogue: C/D layout col = lane&15, row = (lane>>4)*4 + reg  [m89/m91]
  if constexpr (EPI == 7) {
#pragma unroll
    for (int i = 0; i < 4; i++) {
#pragma unroll
      for (int j = 0; j < 4; j += 2) {
        const int ffcol = (((tileN + wn + j * 16) >> 5) << 4) + fm;
#pragma unroll
        for (int r = 0; r < 4; r++) {
          const int rw = tileM + wm + i * 16 + fq * 4 + r;
          float g = acc[i][j][r];
          float u = acc[i][j + 1][r];
          float v = g / (1.f + __expf(-g)) * u;
          outb[(size_t)rw * FF + ffcol] = __float2bfloat16(v);
        }
      }
    }
  } else if constexpr (EPI == 8) {
    __shared__ float lv2[2][128][2];
    __shared__ int   li2[2][128][2];
    const int half = wn >> 6;
#pragma unroll
    for (int i = 0; i < 4; i++) {
#pragma unroll
      for (int r = 0; r < 4; r++) {
        float v0 = -FLT_MAX, v1 = -FLT_MAX;
        int i0 = INT_MAX, i1 = INT_MAX;
#pragma unroll
        for (int j = 0; j < 4; j++) {
          float v = acc[i][j][r];
          int c = tileN + wn + j * 16 + fm;
          if (v > v0) { v1 = v0; i1 = i0; v0 = v; i0 = c; }
          else if (v > v1) { v1 = v; i1 = c; }
        }
#pragma unroll
        for (int off = 1; off < 16; off <<= 1) {
          float w0 = __shfl_xor(v0, off, 64), w1 = __shfl_xor(v1, off, 64);
          int   j0 = __shfl_xor(i0, off, 64), j1 = __shfl_xor(i1, off, 64);
          TKMERGE(w0, j0, w1, j1);
        }
        if (fm == 0) {
          const int lrow = wm + i * 16 + fq * 4 + r;
          lv2[half][lrow][0] = v0; lv2[half][lrow][1] = v1;
          li2[half][lrow][0] = i0; li2[half][lrow][1] = i1;
        }
      }
    }
    __syncthreads();
    if (tid < 128) {
      float v0 = lv2[0][tid][0], v1 = lv2[0][tid][1];
      int   i0 = li2[0][tid][0], i1 = li2[0][tid][1];
      float w0 = lv2[1][tid][0], w1 = lv2[1][tid][1];
      int   j0 = li2[1][tid][0], j1 = li2[1][tid][1];
      TKMERGE(w0, j0, w1, j1);
      float4 c4;
      c4.x = v0; c4.y = v1;
      c4.z = __int_as_float(i0); c4.w = __int_as_float(i1);
      ((float4*)outf)[(size_t)(tileM + tid) * (SS / 128) + (tileN >> 7)] = c4;
    }
  } else {
#pragma unroll
    for (int i = 0; i < 4; i++) {
#pragma unroll
      for (int j = 0; j < 4; j++) {
        const int c = tileN + wn + j * 16 + fm;
#pragma unroll
        for (int r = 0; r < 4; r++) {
          const int rw = tileM + wm + i * 16 + fq * 4 + r;
          const size_t idx = (size_t)rw * N + c;
          float v = acc[i][j][r];
          if constexpr (EPI == 1) {
            v += (c < DD) ? bias0[c] : bias1[c - DD];
            if (c < DD) v = 1.f / (1.f + __expf(-v));
            outb[idx] = __float2bfloat16(v);
          } else if constexpr (EPI == 2) {
            outb[idx] = __float2bfloat16(v);
          } else if constexpr (EPI == 6) {
            outb[(size_t)blockIdx.z * M * N + idx] = __float2bfloat16(v);
          }
        }
      }
    }
  }
}

// ---------------------------------------------------------------------------
// 64x128 (MxN) tile variant for grid-limited N=1024 GEMMs (mix/projout).
// Dual-panel K-loop (LDS 24 KB). EPI 0: bf16(residf_fp32 + acc);
// EPI 3: bf16(residb_bf16 + acc)
// ---------------------------------------------------------------------------
template <int EPI>
__global__ __launch_bounds__(256, 4) void gemm_bt64(
    const __hip_bfloat16* __restrict__ A, const __hip_bfloat16* __restrict__ Bm,
    const int M, const int N, const int K,
    const float* __restrict__ residf, const __hip_bfloat16* __restrict__ residb,
    __hip_bfloat16* __restrict__ outb) {
  __shared__ __align__(16) __hip_bfloat16 As[2][64 * 32];
  __shared__ __align__(16) __hip_bfloat16 Bs[2][128 * 32];
  const int tid = threadIdx.x;
  const int lane = tid & 63;
  const int wave = tid >> 6;
  const int fm = lane & 15, fq = lane >> 4;

  const int nT = gridDim.x;
  const int lin = blockIdx.y * nT + blockIdx.x;
  const int xcd = lin & 7;
  const int idx_ = lin >> 3;
  const int mq = idx_ / nT;
  const int tileM = (xcd * (gridDim.y >> 3) + mq) * 64;
  const int tileN = (idx_ - mq * nT) * 128;

  const int wm = (wave & 1) * 32, wn = (wave >> 1) * 64;

  f32x4 acc[2][4] = {};

  const int srow = tid >> 2;
  const int scol = (tid & 3) * 8;
  const __hip_bfloat16* gA = A + (size_t)(tileM + srow) * K + scol;
  const __hip_bfloat16* gB = Bm + (size_t)(tileN + srow) * K + scol;
  lds_char* ldsA0 = (lds_char*)(&As[0][0]);
  lds_char* ldsA1 = (lds_char*)(&As[1][0]);
  lds_char* ldsB0 = (lds_char*)(&Bs[0][0]);
  lds_char* ldsB1 = (lds_char*)(&Bs[1][0]);
  const int wbyte = wave * 1024;

  for (int k0 = 0; k0 < K; k0 += 64) {
    __syncthreads();
    __builtin_amdgcn_global_load_lds((g_char*)(void*)(gA + k0),                       ldsA0 + wbyte,        16, 0, 0);
    __builtin_amdgcn_global_load_lds((g_char*)(void*)(gB + k0),                       ldsB0 + wbyte,        16, 0, 0);
    __builtin_amdgcn_global_load_lds((g_char*)(void*)(gB + k0 + (size_t)64 * K),      ldsB0 + wbyte + 4096, 16, 0, 0);
    __builtin_amdgcn_global_load_lds((g_char*)(void*)(gA + k0 + 32),                  ldsA1 + wbyte,        16, 0, 0);
    __builtin_amdgcn_global_load_lds((g_char*)(void*)(gB + k0 + 32),                  ldsB1 + wbyte,        16, 0, 0);
    __builtin_amdgcn_global_load_lds((g_char*)(void*)(gB + k0 + 32 + (size_t)64 * K), ldsB1 + wbyte + 4096, 16, 0, 0);
    __syncthreads();
#pragma unroll
    for (int s = 0; s < 2; s++) {
      bf16x8 af[2], bfr[4];
#pragma unroll
      for (int i = 0; i < 2; i++)
        af[i]  = *(const bf16x8*)(&As[s][0] + (wm + i * 16 + fm) * 32 + fq * 8);
#pragma unroll
      for (int j = 0; j < 4; j++)
        bfr[j] = *(const bf16x8*)(&Bs[s][0] + (wn + j * 16 + fm) * 32 + fq * 8);
#pragma unroll
      for (int i = 0; i < 2; i++)
#pragma unroll
        for (int j = 0; j < 4; j++)
          acc[i][j] = __builtin_amdgcn_mfma_f32_16x16x32_bf16(af[i], bfr[j], acc[i][j], 0, 0, 0);
    }
  }

#pragma unroll
  for (int i = 0; i < 2; i++) {
#pragma unroll
    for (int j = 0; j < 4; j++) {
      const int c = tileN + wn + j * 16 + fm;
#pragma unroll
      for (int r = 0; r < 4; r++) {
        const int rw = tileM + wm + i * 16 + fq * 4 + r;
        const size_t idx = (size_t)rw * N + c;
        float v = acc[i][j][r];
        if constexpr (EPI == 0) {
          outb[idx] = __float2bfloat16(residf[idx] + v);
        } else {
          outb[idx] = __float2bfloat16(__bfloat162float(residb[idx]) + v);
        }
      }
    }
  }
}

// ---------------------------------------------------------------------------
// split-K fixup for the down projection: out_fp32 = resid_bf16 + P0 + P1
// ---------------------------------------------------------------------------
__global__ __launch_bounds__(256) void reduce_final(const __hip_bfloat16* __restrict__ P,
                                                    const __hip_bfloat16* __restrict__ resid,
                                                    float* __restrict__ out) {
  size_t i = (size_t)blockIdx.x * 256 + threadIdx.x;
  bf16x8 a = ((const bf16x8*)P)[i];
  bf16x8 b = ((const bf16x8*)(P + (size_t)MTOK * DD))[i];
  bf16x8 rr = ((const bf16x8*)resid)[i];
  float o[8];
#pragma unroll
  for (int k = 0; k < 8; k++)
    o[k] = (float)rr[k] + (float)a[k] + (float)b[k];
  float4 o0 = {o[0], o[1], o[2], o[3]};
  float4 o1 = {o[4], o[5], o[6], o[7]};
  ((float4*)out)[i * 2]     = o0;
  ((float4*)out)[i * 2 + 1] = o1;
}

// ---------------------------------------------------------------------------
// MinGRU chunked parallel scan over zht [MTOK, 2048] bf16 (z | htilde)
// ---------------------------------------------------------------------------
__global__ __launch_bounds__(256) void scan_pass1(const __hip_bfloat16* __restrict__ zht,
                                                  float* __restrict__ cA,
                                                  float* __restrict__ cB) {
  const int b = blockIdx.z, c = blockIdx.y;
  const int d = blockIdx.x * 256 + threadIdx.x;
  const __hip_bfloat16* base = zht + (size_t)b * TT * 2048;
  float A = 1.f, Bc = 0.f;
  const int t0 = c * TCHUNK;
  for (int t = t0; t < t0 + TCHUNK; t++) {
    const __hip_bfloat16* rowp = base + (size_t)t * 2048;
    float z = __bfloat162float(rowp[d]);
    float h = __bfloat162float(rowp[DD + d]);
    float om = 1.f - z;
    A *= om;
    Bc = om * Bc + z * h;
  }
  size_t idx = ((size_t)b * NCHUNK + c) * DD + d;
  cA[idx] = A;
  cB[idx] = Bc;
}

__global__ __launch_bounds__(256) void scan_pass2(const float* __restrict__ hp,
                                                  const float* __restrict__ cA,
                                                  const float* __restrict__ cB,
                                                  float* __restrict__ hstart,
                                                  float* __restrict__ hlast) {
  const int b = blockIdx.y;
  const int d = blockIdx.x * 256 + threadIdx.x;
  float h = hp[b * DD + d];
  for (int c = 0; c < NCHUNK; c++) {
    size_t idx = ((size_t)b * NCHUNK + c) * DD + d;
    hstart[idx] = h;
    h = cA[idx] * h + cB[idx];
  }
  hlast[b * DD + d] = h;
}

__global__ __launch_bounds__(256) void scan_pass3(const __hip_bfloat16* __restrict__ zht,
                                                  const float* __restrict__ hstart,
                                                  __hip_bfloat16* __restrict__ x) {
  const int b = blockIdx.z, c = blockIdx.y;
  const int d = blockIdx.x * 256 + threadIdx.x;
  const __hip_bfloat16* base = zht + (size_t)b * TT * 2048;
  float h = hstart[((size_t)b * NCHUNK + c) * DD + d];
  const int t0 = c * TCHUNK;
  for (int t = t0; t < t0 + TCHUNK; t++) {
    const __hip_bfloat16* rowp = base + (size_t)t * 2048;
    float z = __bfloat162float(rowp[d]);
    float ht = __bfloat162float(rowp[DD + d]);
    h = (1.f - z) * h + z * ht;
    size_t xi = ((size_t)b * TT + t) * DD + d;
    x[xi] = __float2bfloat16(__bfloat162float(x[xi]) + h);
  }
}

// ---------------------------------------------------------------------------
// merge 32 per-tile top-2 candidates per row -> global top-2, softmax, gather
// (slot_values in bf16). One wave per row; 4 rows per block.
// ---------------------------------------------------------------------------
__global__ __launch_bounds__(256) void topk_merge(const float4* __restrict__ cand,
                                                  const __hip_bfloat16* __restrict__ svb,
                                                  __hip_bfloat16* __restrict__ ret) {
  const int row = blockIdx.x * 4 + (threadIdx.x >> 6);
  const int lane = threadIdx.x & 63;
  float v0 = -FLT_MAX, v1 = -FLT_MAX;
  int i0 = INT_MAX, i1 = INT_MAX;
  if (lane < 32) {
    float4 c = cand[(size_t)row * 32 + lane];
    v0 = c.x; v1 = c.y;
    i0 = __float_as_int(c.z); i1 = __float_as_int(c.w);
  }
#pragma unroll
  for (int off = 1; off < 64; off <<= 1) {
    float w0 = __shfl_xor(v0, off, 64), w1 = __shfl_xor(v1, off, 64);
    int   j0 = __shfl_xor(i0, off, 64), j1 = __shfl_xor(i1, off, 64);
    TKMERGE(w0, j0, w1, j1);
  }
  float s0 = v0 * (1.f / 32.f), s1 = v1 * (1.f / 32.f);  // /sqrt(D)
  float e = __expf(s1 - s0);
  float denom = 1.f + e;
  float a0 = 1.f / denom;
  float a1 = e / denom;
  const bf16x8* r0 = (const bf16x8*)(svb + (size_t)i0 * DD);
  const bf16x8* r1 = (const bf16x8*)(svb + (size_t)i1 * DD);
#pragma unroll
  for (int k = 0; k < 2; k++) {
    int j = lane + 64 * k;
    bf16x8 u = r0[j], w8 = r1[j];
    bf16x8 res;
#pragma unroll
    for (int t = 0; t < 8; t++)
      res[t] = (__bf16)(a0 * (float)u[t] + a1 * (float)w8[t]);
    ((bf16x8*)(ret + (size_t)row * DD))[j] = res;
  }
}

// ---------------------------------------------------------------------------
extern "C" void kernel_launch(void* const* d_in, const int* in_sizes, int n_in,
                              void* d_out, int out_size, void* d_ws, size_t ws_size,
                              hipStream_t stream) {
  (void)in_sizes; (void)n_in; (void)out_size; (void)ws_size;
  const float* x_in   = (const float*)d_in[0];
  const float* h_prev = (const float*)d_in[1];
  const float* n1w    = (const float*)d_in[2];
  const float* w3     = (const float*)d_in[3];
  const float* w7     = (const float*)d_in[4];
  const float* w15    = (const float*)d_in[5];
  const float* mixw   = (const float*)d_in[6];
  const float* n2w    = (const float*)d_in[7];
  const float* wzw    = (const float*)d_in[8];
  const float* wzb    = (const float*)d_in[9];
  const float* whw    = (const float*)d_in[10];
  const float* whb    = (const float*)d_in[11];
  const float* n3w    = (const float*)d_in[12];
  const float* slotk  = (const float*)d_in[13];
  const float* slotv  = (const float*)d_in[14];
  const float* pqw    = (const float*)d_in[15];
  const float* pow_   = (const float*)d_in[16];
  const float* n4w    = (const float*)d_in[17];
  const float* gatew  = (const float*)d_in[18];
  const float* upw    = (const float*)d_in[19];
  const float* downw  = (const float*)d_in[20];
  float* out = (float*)d_out;

  char* ws = (char*)d_ws;
  size_t o = 0;
  auto alloc = [&](size_t bytes) {
    size_t r = o;
    o += (bytes + 255) & ~(size_t)255;
    return r;
  };
  __hip_bfloat16* wmix = (__hip_bfloat16*)(ws + alloc((size_t)DD * DD * 2));
  __hip_bfloat16* wzht = (__hip_bfloat16*)(ws + alloc((size_t)2 * DD * DD * 2));
  __hip_bfloat16* wpqT = (__hip_bfloat16*)(ws + alloc((size_t)DD * DD * 2));  // projq^T
  __hip_bfloat16* wsk  = (__hip_bfloat16*)(ws + alloc((size_t)SS * DD * 2));
  __hip_bfloat16* wpo  = (__hip_bfloat16*)(ws + alloc((size_t)DD * DD * 2));
  __hip_bfloat16* wfu  = (__hip_bfloat16*)(ws + alloc((size_t)2 * FF * DD * 2));  // gate/up interleaved
  __hip_bfloat16* wd   = (__hip_bfloat16*)(ws + alloc((size_t)DD * FF * 2));
  __hip_bfloat16* w2b  = (__hip_bfloat16*)(ws + alloc((size_t)SS * DD * 2));  // slot_keys @ projq
  __hip_bfloat16* svb  = (__hip_bfloat16*)(ws + alloc((size_t)SS * DD * 2));  // slot_values bf16
  float* wcomb = (float*)(ws + alloc((size_t)DD * 16 * 4));
  __hip_bfloat16* xws  = (__hip_bfloat16*)(ws + alloc((size_t)MTOK * DD * 2));  // bf16 residual stream
  __hip_bfloat16* xnb  = (__hip_bfloat16*)(ws + alloc((size_t)MTOK * DD * 2));
  __hip_bfloat16* retr = (__hip_bfloat16*)(ws + alloc((size_t)MTOK * DD * 2));
  float* scanA  = (float*)(ws + alloc((size_t)BB * NCHUNK * DD * 4));
  float* scanB  = (float*)(ws + alloc((size_t)BB * NCHUNK * DD * 4));
  float* hstart = (float*)(ws + alloc((size_t)BB * NCHUNK * DD * 4));
  char* big = ws + alloc((size_t)MTOK * FF * 4);  // 134 MB shared region
  // aliases (lifetimes disjoint):
  __hip_bfloat16* xn1b  = (__hip_bfloat16*)big;                            // phase 1
  __hip_bfloat16* convb = (__hip_bfloat16*)(big + (size_t)MTOK * DD * 2);  // phase 1
  __hip_bfloat16* zhtb  = (__hip_bfloat16*)big;                            // phase 2
  float* candf          = (float*)big;                                     // phase 3 (4 MB)
  __hip_bfloat16* ffin  = (__hip_bfloat16*)big;                            // phase 4
  __hip_bfloat16* Pbuf  = (__hip_bfloat16*)(big + (size_t)MTOK * FF * 2);  // phase 4 (2x16.7MB bf16)

  // weight conversions — one batched dispatch
  {
    CvtArgs a;
    const float* srcs[10] = {mixw, wzw, whw, pqw, slotk, pow_, gatew, upw, downw, slotv};
    __hip_bfloat16* dsts[10] = {wmix, wzht, wzht + (size_t)DD * DD, wpqT, wsk, wpo, wfu, wfu, wd, svb};
    int n4s[10] = {DD * DD / 4, DD * DD / 4, DD * DD / 4, DD * DD / 4, SS * DD / 4,
                   DD * DD / 4, FF * DD / 4, FF * DD / 4, DD * FF / 4, SS * DD / 4};
    int modes[10] = {0, 0, 0, 3, 0, 0, 1, 2, 0, 0};
    int acc_ = 0;
    for (int i = 0; i < 10; i++) {
      a.src[i] = srcs[i]; a.dst[i] = dsts[i]; a.off4[i] = acc_; a.mode[i] = modes[i];
      acc_ += n4s[i];
    }
    a.off4[10] = acc_;
    cvt_all_kernel<<<(acc_ + 255) / 256, 256, 0, stream>>>(a);
  }
  wcomb_kernel<<<DD / 256, 256, 0, stream>>>(w3, w7, w15, wcomb);
  // fold projq into slot_keys: W2[S,D] = slot_keys @ projq  (B = projq^T)
  gemm_bt<2, 1, 0><<<dim3(DD / 128, SS / 128), 256, 0, stream>>>(
      wsk, wpqT, SS, DD, DD, nullptr, w2b, nullptr, nullptr);

  // 1. conv block
  rms_kernel<0><<<MTOK, 256, 0, stream>>>(x_in, n1w, xn1b);
  conv_kernel<<<dim3(TT / 64, DD / 64, BB), 256, 0, stream>>>(xn1b, wcomb, convb);
  gemm_bt64<0><<<dim3(DD / 128, MTOK / 64), 256, 0, stream>>>(
      convb, wmix, MTOK, DD, DD, x_in, nullptr, xws);

  // 2. MinGRU
  rms_kernel<1><<<MTOK, 256, 0, stream>>>(xws, n2w, xnb);
  gemm_bt<1, 1, 0><<<dim3(2048 / 128, MTOK / 128), 256, 0, stream>>>(
      xnb, wzht, MTOK, 2048, DD, nullptr, zhtb, wzb, whb);
  scan_pass1<<<dim3(DD / 256, NCHUNK, BB), 256, 0, stream>>>(zhtb, scanA, scanB);
  scan_pass2<<<dim3(DD / 256, BB), 256, 0, stream>>>(h_prev, scanA, scanB, hstart,
                                                     out + (size_t)MTOK * DD);
  scan_pass3<<<dim3(DD / 256, NCHUNK, BB), 256, 0, stream>>>(zhtb, hstart, xws);

  // 3. slot memory (scores = xn @ W2^T directly; top-2 fused into epilogue)
  rms_kernel<1><<<MTOK, 256, 0, stream>>>(xws, n3w, xnb);
  gemm_bt<8, 1, 1><<<dim3(SS / 128, MTOK / 128), 256, 0, stream>>>(
      xnb, w2b, MTOK, SS, DD, candf, nullptr, nullptr, nullptr);
  topk_merge<<<MTOK / 4, 256, 0, stream>>>((const float4*)candf, svb, retr);
  gemm_bt64<3><<<dim3(DD / 128, MTOK / 64), 256, 0, stream>>>(
      retr, wpo, MTOK, DD, DD, nullptr, xws, xws);

  // 4. SwiGLU FFN (fused gate+up, then split-K down + reduce)
  rms_kernel<1><<<MTOK, 256, 0, stream>>>(xws, n4w, xnb);
  gemm_bt<7, 1, 1><<<dim3(2 * FF / 128, MTOK / 128), 256, 0, stream>>>(
      xnb, wfu, MTOK, 2 * FF, DD, nullptr, ffin, nullptr, nullptr);
  gemm_bt<6, 2, 0><<<dim3(DD / 128, MTOK / 128, 2), 256, 0, stream>>>(
      ffin, wd, MTOK, DD, FF, nullptr, Pbuf, nullptr, nullptr);
  reduce_final<<<MTOK * DD / 2048, 256, 0, stream>>>(Pbuf, xws, out);
}